// Round 3
// baseline (20047.459 us; speedup 1.0000x reference)
//
#include <hip/hip_runtime.h>
#include <stdint.h>

#define SLEN 128
#define NW 8192          // B*S words
#define WCH 16           // chars per word
#define EDIM 256
#define HDIM 512
#define G4 2048          // 4*H word-gate width
#define CH 1024          // char hidden (2H)
#define CG 4096          // 4*CH char-gate width
#define NCLS 20

typedef __attribute__((ext_vector_type(4))) float f32x4;
typedef __attribute__((ext_vector_type(8))) short s16x8;

__device__ __forceinline__ ushort f2b(float f){
  uint32_t u = __float_as_uint(f);
  return (ushort)((u + 0x7FFFu + ((u>>16)&1u)) >> 16);
}
__device__ __forceinline__ float b2f(ushort s){ return __uint_as_float(((uint32_t)s)<<16); }
__device__ __forceinline__ float sigf(float x){ return 1.f/(1.f+__expf(-x)); }
__device__ __forceinline__ float tanhf_(float x){
  float t = fminf(fmaxf(2.f*x,-30.f),30.f);
  float e = __expf(t);
  return (e-1.f)/(e+1.f);
}

__device__ __forceinline__ void gl16(const ushort* g, ushort* l){
  __builtin_amdgcn_global_load_lds((const __attribute__((address_space(1))) uint32_t*)g,
                                   (__attribute__((address_space(3))) uint32_t*)l, 16, 0, 0);
}

// ---------- utility ----------
__global__ void k_fill(uint32_t* __restrict__ p, uint32_t v, int n){
  int i = blockIdx.x*256 + threadIdx.x;
  if (i < n) p[i] = v;
}

__global__ void k_cvt(const float* __restrict__ s, ushort* __restrict__ d, int n){
  int i = blockIdx.x*256 + threadIdx.x;
  if (i < n) d[i] = f2b(s[i]);
}

// permute c_Whh rows: dst row dr = nb*128 + g*32 + wn*16 + hl  <-  src row g*1024 + (nb*32+wn*16+hl)
__global__ void k_cwhhp(const float* __restrict__ s, ushort* __restrict__ d){
  int i = blockIdx.x*256 + threadIdx.x;           // over 4096*1024
  int dr = i >> 10, k = i & 1023;
  int nb = dr >> 7, w7 = dr & 127;
  int g = w7 >> 5, wn = (w7>>4)&1, hl = w7&15;
  int h = nb*32 + wn*16 + hl;
  d[i] = f2b(s[(size_t)(g*1024 + h)*1024 + k]);
}

__global__ void k_emb(const int* __restrict__ words, const float* __restrict__ we,
                      ushort* __restrict__ d){
  int i = blockIdx.x*256 + threadIdx.x;           // NW*EDIM
  int w = i >> 8, e = i & 255;
  d[i] = f2b(we[(size_t)words[w]*EDIM + e]);
}

// char_proj[c][perm_col] = c_b[j] + char_emb[c] . c_Wih[j]   (perm layout as k_cwhhp)
__global__ void k_cproj(const float* __restrict__ cemb, const float* __restrict__ cwih,
                        const float* __restrict__ cb, float* __restrict__ out){
  int i = blockIdx.x*256 + threadIdx.x;           // 128*4096
  int c = i >> 12, p = i & 4095;
  int nb = p >> 7, w7 = p & 127;
  int g = w7>>5, wn = (w7>>4)&1, hl = w7&15;
  int j = g*1024 + nb*32 + wn*16 + hl;
  const float* a = cemb + (size_t)c*EDIM;
  const float* b = cwih + (size_t)j*EDIM;
  float acc = cb[j];
  for (int k=0;k<EDIM;k+=4){
    float4 av = *(const float4*)&a[k]; float4 bv = *(const float4*)&b[k];
    acc += av.x*bv.x + av.y*bv.y + av.z*bv.z + av.w*bv.w;
  }
  out[i] = acc;
}

__global__ void k_hist(const int* __restrict__ wn, const int* __restrict__ cl,
                       int* __restrict__ cnt17){
  int w = blockIdx.x*256 + threadIdx.x; if (w >= NW) return;
  int b = w >> 7, s = w & 127;
  if (s < wn[b]) atomicAdd(&cnt17[cl[w]], 1);   // cl in [1,16]
}

__global__ void k_scan(const int* __restrict__ cnt17, int* __restrict__ cnt_step,
                       int* __restrict__ cur){
  if (threadIdx.x==0 && blockIdx.x==0){
    cnt_step[16] = 0;
    for (int t=15;t>=0;t--) cnt_step[t] = cnt_step[t+1] + cnt17[t+1];
    for (int l=1;l<=16;l++) cur[l] = cnt_step[l];   // bucket cursors (len descending order)
  }
}

__global__ void k_scatter(const int* __restrict__ wn, const int* __restrict__ cl,
                          const int* __restrict__ chars, int* __restrict__ cur,
                          int* __restrict__ inv, int* __restrict__ chperm){
  int w = blockIdx.x*256 + threadIdx.x; if (w >= NW) return;
  int b = w >> 7, s = w & 127;
  if (s < wn[b]){
    int len = cl[w];
    int pos = atomicAdd(&cur[len], 1);
    inv[w] = pos;
    for (int j=0;j<WCH;j++) chperm[pos*WCH + j] = chars[w*WCH + j];
  }
}

// ---------- MFMA GEMM: C = A[M,K] @ B[N,K]^T, bf16 in, fp32 acc ----------
// EPI=0: X projection (out bf16 = acc + bias[col]), grid (M/128, N/128, ndir)
// EPI=1: char-LSTM step epilogue (gate fusion), grid (64, 32, 1)
template<int EPI>
__global__ __launch_bounds__(256) void k_gemm(
    const ushort* __restrict__ A, int ldA,
    const ushort* __restrict__ Bm, int ldB, size_t bStrideZ,
    ushort* __restrict__ outX, const float* __restrict__ bias,
    size_t oStrideZ, size_t biasStrideZ, int K,
    const int* __restrict__ cnt_step, int tstep,
    const int* __restrict__ chperm, const float* __restrict__ cproj,
    float* __restrict__ ccell, ushort* __restrict__ hcdst)
{
  int cntv = 0;
  if (EPI==1){ cntv = cnt_step[tstep]; if ((int)(blockIdx.x*128) >= cntv) return; }
  __shared__ __align__(16) ushort As[128*64];
  __shared__ __align__(16) ushort Bs[128*64];
  int tid = threadIdx.x, wid = tid>>6, lane = tid&63;
  int wm = wid>>1, wn = wid&1;
  int l15 = lane&15, l4 = lane>>4;
  const ushort* Ab = A + (size_t)blockIdx.x*128*ldA;
  const ushort* Bb = Bm + (size_t)blockIdx.z*bStrideZ + (size_t)blockIdx.y*128*ldB;
  f32x4 acc[4][4];
  #pragma unroll
  for (int i=0;i<4;i++)
    #pragma unroll
    for (int j=0;j<4;j++) acc[i][j] = f32x4{0.f,0.f,0.f,0.f};

  for (int k0=0; k0<K; k0+=64){
    // stage A and B tiles; LDS dest linear per-wave, global source pre-swizzled:
    // LDS 16B-slot cp of row holds global chunk c = cp ^ (row&7)
    #pragma unroll
    for (int i=0;i<4;i++){
      int fcb = (i*4 + wid)*64;
      int fc = fcb + lane;
      int row = fc>>3, cp = fc&7, c = cp ^ (row&7);
      gl16(Ab + (size_t)row*ldA + k0 + c*8, As + fcb*8);
    }
    #pragma unroll
    for (int i=0;i<4;i++){
      int fcb = (i*4 + wid)*64;
      int fc = fcb + lane;
      int row = fc>>3, cp = fc&7, c = cp ^ (row&7);
      gl16(Bb + (size_t)row*ldB + k0 + c*8, Bs + fcb*8);
    }
    __syncthreads();
    #pragma unroll
    for (int kw=0; kw<2; kw++){
      s16x8 af[4], bfr[4];
      #pragma unroll
      for (int mf=0; mf<4; mf++){
        int r = wm*64 + mf*16 + l15;
        int slot = (kw*4 + l4) ^ (r&7);
        af[mf] = *(const s16x8*)&As[r*64 + slot*8];
      }
      #pragma unroll
      for (int nf=0; nf<4; nf++){
        int r = (EPI==1) ? (nf*32 + wn*16 + l15) : (wn*64 + nf*16 + l15);
        int slot = (kw*4 + l4) ^ (r&7);
        bfr[nf] = *(const s16x8*)&Bs[r*64 + slot*8];
      }
      #pragma unroll
      for (int mf=0; mf<4; mf++)
        #pragma unroll
        for (int nf=0; nf<4; nf++)
          acc[mf][nf] = __builtin_amdgcn_mfma_f32_16x16x32_bf16(af[mf], bfr[nf], acc[mf][nf], 0,0,0);
    }
    __syncthreads();
  }

  if (EPI==0){
    ushort* op = outX + blockIdx.z*oStrideZ;
    const float* bp = bias + blockIdx.z*biasStrideZ;
    #pragma unroll
    for (int mf=0; mf<4; mf++){
      #pragma unroll
      for (int r=0;r<4;r++){
        int row = blockIdx.x*128 + wm*64 + mf*16 + l4*4 + r;
        #pragma unroll
        for (int nf=0;nf<4;nf++){
          int col = blockIdx.y*128 + wn*64 + nf*16 + l15;
          op[(size_t)row*G4 + col] = f2b(acc[mf][nf][r] + bp[col]);
        }
      }
    }
  } else {
    int hb = blockIdx.y*32 + wn*16 + l15;     // h index in [0,1024)
    #pragma unroll
    for (int mf=0; mf<4; mf++){
      #pragma unroll
      for (int r=0;r<4;r++){
        int row = blockIdx.x*128 + wm*64 + mf*16 + l4*4 + r;
        if (row < cntv){
          int cid = chperm[row*WCH + tstep];
          const float* cp = cproj + (size_t)cid*CG + blockIdx.y*128 + wn*16 + l15;
          float zi = acc[mf][0][r] + cp[0];
          float zf = acc[mf][1][r] + cp[32];
          float zg = acc[mf][2][r] + cp[64];
          float zo = acc[mf][3][r] + cp[96];
          size_t ix = (size_t)row*CH + hb;
          float c = ccell[ix];
          float cn = sigf(zf)*c + sigf(zi)*tanhf_(zg);
          ccell[ix] = cn;
          hcdst[ix] = f2b(sigf(zo)*tanhf_(cn));
        }
      }
    }
  }
}

// ---------- word-path LSTM step (fwd+bwd fused), fp32 ----------
// grid 512: blocks [0,256)=fwd, [256,512)=bwd ; each block owns 2 h-indices (8 gate cols)
__global__ __launch_bounds__(256) void k_step(
    const ushort* __restrict__ X,       // [2][NW][G4] bf16 (x@Wih^T + b)
    const float* __restrict__ Whh,      // [2][G4][HDIM]
    const float* __restrict__ hsrc,     // [2][64][HDIM]
    float* __restrict__ hdst,
    float* __restrict__ cst,            // [2][64][HDIM]
    const int* __restrict__ lens,
    ushort* __restrict__ outcat,        // [NW][1024] bf16
    int t)
{
  __shared__ float zsh[8][64];
  int tid = threadIdx.x;
  int dir = blockIdx.x >> 8;
  int nb  = blockIdx.x & 255;
  int h0 = nb*2;
  int zc = tid>>5, bl = tid&31;
  int hl = zc>>2, gate = zc&3;
  int j = gate*HDIM + h0 + hl;
  const float* wr = Whh + ((size_t)dir*G4 + j)*HDIM;
  const float* ha = hsrc + ((size_t)dir*64 + bl)*HDIM;
  const float* hb = hsrc + ((size_t)dir*64 + bl+32)*HDIM;
  float a0=0.f, a1=0.f;
  #pragma unroll 4
  for (int k=0;k<HDIM;k+=4){
    float4 w = *(const float4*)&wr[k];
    float4 p = *(const float4*)&ha[k];
    float4 q = *(const float4*)&hb[k];
    a0 += w.x*p.x + w.y*p.y + w.z*p.z + w.w*p.w;
    a1 += w.x*q.x + w.y*q.y + w.z*q.z + w.w*q.w;
  }
  {
    int len = lens[bl];
    if (t < len){
      int pos = dir ? (len-1-t) : t;
      a0 += b2f(X[((size_t)dir*NW + bl*SLEN + pos)*G4 + j]);
    }
    int len2 = lens[bl+32];
    if (t < len2){
      int pos = dir ? (len2-1-t) : t;
      a1 += b2f(X[((size_t)dir*NW + (bl+32)*SLEN + pos)*G4 + j]);
    }
  }
  zsh[zc][bl] = a0;
  zsh[zc][bl+32] = a1;
  __syncthreads();
  if (tid < 128){
    int hl2 = tid>>6, b = tid&63;
    int hidx = h0 + hl2;
    size_t six = ((size_t)dir*64 + b)*HDIM + hidx;
    int len = lens[b];
    float hv = hsrc[six];
    if (t < len){
      float zi = zsh[hl2*4+0][b], zf = zsh[hl2*4+1][b];
      float zg = zsh[hl2*4+2][b], zo = zsh[hl2*4+3][b];
      float c = cst[six];
      float cn = sigf(zf)*c + sigf(zi)*tanhf_(zg);
      cst[six] = cn;
      hv = sigf(zo)*tanhf_(cn);
      int pos = dir ? (len-1-t) : t;
      outcat[((size_t)b*SLEN + pos)*1024 + dir*HDIM + hidx] = f2b(hv);
    }
    hdst[six] = hv;   // carry frozen state forward
  }
}

// ---------- gather final char h into word order (zeros for invalid words) ----------
__global__ void k_gather(const ushort* __restrict__ hc0, const ushort* __restrict__ hc1,
                         const int* __restrict__ inv, const int* __restrict__ cl,
                         ushort* __restrict__ ycat){
  int i = blockIdx.x*256 + threadIdx.x;     // over NW*128 (16B each)
  if (i >= NW*128) return;
  int w = i >> 7, seg = i & 127;
  int iv = inv[w];
  ulonglong2 z; z.x = 0; z.y = 0;
  if (iv >= 0){
    const ushort* src = (((cl[w]-1)&1) ? hc0 : hc1) + (size_t)iv*CH + seg*8;
    z = *(const ulonglong2*)src;
  }
  *(ulonglong2*)(ycat + (size_t)w*CH + seg*8) = z;
}

// ---------- final linear ----------
__global__ __launch_bounds__(256) void k_final(
    const ushort* __restrict__ h1cat, const ushort* __restrict__ ycat,
    const float* __restrict__ lw, const float* __restrict__ lb,
    float* __restrict__ out)
{
  int i = blockIdx.x*256 + threadIdx.x;
  if (i >= NW*NCLS) return;
  int w = i / NCLS, o = i - w*NCLS;
  const ushort* hr = h1cat + (size_t)w*1024;
  const ushort* yr = ycat  + (size_t)w*1024;
  const float* wr = lw + (size_t)o*1024;
  float acc = lb[o];
  for (int k=0;k<1024;k+=4){
    float4 wv = *(const float4*)&wr[k];
    ushort4 a4 = *(const ushort4*)&hr[k];
    ushort4 b4 = *(const ushort4*)&yr[k];
    acc += (b2f(a4.x)+b2f(b4.x))*wv.x + (b2f(a4.y)+b2f(b4.y))*wv.y
         + (b2f(a4.z)+b2f(b4.z))*wv.z + (b2f(a4.w)+b2f(b4.w))*wv.w;
  }
  out[i] = acc;
}

extern "C" void kernel_launch(void* const* d_in, const int* in_sizes, int n_in,
                              void* d_out, int out_size, void* d_ws, size_t ws_size,
                              hipStream_t stream)
{
  const int*   words = (const int*)d_in[0];
  const int*   wnum  = (const int*)d_in[1];
  const int*   chars = (const int*)d_in[2];
  const int*   clens = (const int*)d_in[3];
  const float* wemb  = (const float*)d_in[4];
  const float* cemb  = (const float*)d_in[5];
  const float* l0Wih = (const float*)d_in[6];
  const float* l0Whh = (const float*)d_in[7];
  const float* l0b   = (const float*)d_in[8];
  const float* l1Wih = (const float*)d_in[9];
  const float* l1Whh = (const float*)d_in[10];
  const float* l1b   = (const float*)d_in[11];
  const float* cWih  = (const float*)d_in[12];
  const float* cWhh  = (const float*)d_in[13];
  const float* cb    = (const float*)d_in[14];
  const float* linW  = (const float*)d_in[15];
  const float* linb  = (const float*)d_in[16];
  float* out = (float*)d_out;

  // ---- static workspace layout (peak ~111 MB); char phase aliases word phase ----
  char* base = (char*)d_ws;
  const size_t MB = (size_t)1<<20;
  ushort* hc0    = (ushort*)(base);            // 16 MB (char)  | X region (word)
  ushort* hc1    = (ushort*)(base + 16*MB);    // 16 MB (char)  |
  float*  ccell  = (float*) (base + 32*MB);    // 32 MB (char)  |
  ushort* X      = (ushort*)(base);            // 64 MB (word)
  ushort* cwp    = (ushort*)(base + 64*MB);    //  8 MB (char)  | l1w 8MB (word)
  ushort* l1w    = (ushort*)(base + 64*MB);
  float*  cproj  = (float*) (base + 72*MB);    //  2 MB (char)  | embw 4MB (word)
  int*    chperm = (int*)   (base + 74*MB);    // 512 KB (char) |
  ushort* embw   = (ushort*)(base + 72*MB);
  ushort* ycat   = (ushort*)(base + 76*MB);    // 16 MB persistent
  ushort* h0cat  = (ushort*)(base + 92*MB);    // 16 MB (layer0 out) | h1cat after X1 GEMM
  ushort* h1cat  = (ushort*)(base + 92*MB);
  ushort* l0w    = (ushort*)(base + 108*MB);   //  2 MB
  float*  hstA   = (float*) (base + 110*MB);               // 256 KB
  float*  hstB   = (float*) (base + 110*MB + 256*1024);    // 256 KB
  float*  cstw   = (float*) (base + 110*MB + 512*1024);    // 256 KB
  int*    inv    = (int*)   (base + 110*MB + 768*1024);    // 32 KB
  int*    cnt17  = (int*)   (base + 110*MB + 800*1024);    // 68 B
  int*    cntstep= (int*)   (base + 110*MB + 801*1024);    // 68 B
  int*    cur    = (int*)   (base + 110*MB + 802*1024);    // 68 B

  // ---- phase 0: char-path prep ----
  k_fill<<<1, 256, 0, stream>>>((uint32_t*)cnt17, 0u, 17);
  k_fill<<<(NW+255)/256, 256, 0, stream>>>((uint32_t*)inv, 0xFFFFFFFFu, NW);
  k_fill<<<(NW*CH/2+255)/256, 256, 0, stream>>>((uint32_t*)hc0, 0u, NW*CH/2);
  k_fill<<<(NW*CH+255)/256, 256, 0, stream>>>((uint32_t*)ccell, 0u, NW*CH);
  k_cwhhp<<<(CG*CH)/256, 256, 0, stream>>>(cWhh, cwp);
  k_cproj<<<(128*CG)/256, 256, 0, stream>>>(cemb, cWih, cb, cproj);
  k_hist<<<NW/256, 256, 0, stream>>>(wnum, clens, cnt17);
  k_scan<<<1, 1, 0, stream>>>(cnt17, cntstep, cur);
  k_scatter<<<NW/256, 256, 0, stream>>>(wnum, clens, chars, cur, inv, chperm);

  // ---- phase 1: char LSTM, 16 fused GEMM+gate steps over len-sorted valid words ----
  for (int t=0;t<WCH;t++){
    const ushort* hs = (t&1)? hc1 : hc0;
    ushort*       hd = (t&1)? hc0 : hc1;
    k_gemm<1><<<dim3(64,32,1), 256, 0, stream>>>(hs, CH, cwp, CH, 0,
        nullptr, nullptr, 0, 0, CH,
        cntstep, t, chperm, cproj, ccell, hd);
  }
  // ---- phase 2: gather final char h to word order; frees the 64MB char region ----
  k_gather<<<(NW*128+255)/256, 256, 0, stream>>>(hc0, hc1, inv, clens, ycat);

  // ---- phase 3: word path ----
  k_cvt<<<(2*G4*EDIM+255)/256, 256, 0, stream>>>(l0Wih, l0w, 2*G4*EDIM);
  k_cvt<<<(2*G4*1024+255)/256, 256, 0, stream>>>(l1Wih, l1w, 2*G4*1024);
  k_emb<<<(NW*EDIM)/256, 256, 0, stream>>>(words, wemb, embw);
  k_fill<<<(NW*512+255)/256, 256, 0, stream>>>((uint32_t*)h0cat, 0u, NW*512);
  k_fill<<<(65536+255)/256, 256, 0, stream>>>((uint32_t*)hstA, 0u, 65536);
  k_fill<<<(65536+255)/256, 256, 0, stream>>>((uint32_t*)cstw, 0u, 65536);

  // X0 = emb @ l0_Wih^T + b  (both dirs)
  k_gemm<0><<<dim3(64,16,2), 256, 0, stream>>>(embw, EDIM, l0w, EDIM, (size_t)G4*EDIM,
      X, l0b, (size_t)NW*G4, (size_t)G4, EDIM,
      nullptr, 0, nullptr, nullptr, nullptr, nullptr);

  for (int t=0;t<SLEN;t++){
    const float* hs = (t&1)? hstB : hstA;
    float*       hd = (t&1)? hstA : hstB;
    k_step<<<512, 256, 0, stream>>>(X, l0Whh, hs, hd, cstw, wnum, h0cat, t);
  }

  k_fill<<<(65536+255)/256, 256, 0, stream>>>((uint32_t*)hstA, 0u, 65536);
  k_fill<<<(65536+255)/256, 256, 0, stream>>>((uint32_t*)cstw, 0u, 65536);

  // X1 = h0cat @ l1_Wih^T + b   (fully consumes h0cat; h1cat aliases it afterwards)
  k_gemm<0><<<dim3(64,16,2), 256, 0, stream>>>(h0cat, 1024, l1w, 1024, (size_t)G4*1024,
      X, l1b, (size_t)NW*G4, (size_t)G4, 1024,
      nullptr, 0, nullptr, nullptr, nullptr, nullptr);

  k_fill<<<(NW*512+255)/256, 256, 0, stream>>>((uint32_t*)h1cat, 0u, NW*512);

  for (int t=0;t<SLEN;t++){
    const float* hs = (t&1)? hstB : hstA;
    float*       hd = (t&1)? hstA : hstB;
    k_step<<<512, 256, 0, stream>>>(X, l1Whh, hs, hd, cstw, wnum, h1cat, t);
  }

  k_final<<<(NW*NCLS+255)/256, 256, 0, stream>>>(h1cat, ycat, linW, linb, out);
}

// Round 4
// 8012.158 us; speedup vs baseline: 2.5021x; 2.5021x over previous
//
#include <hip/hip_runtime.h>
#include <stdint.h>

#define SLEN 128
#define NW 8192          // B*S words
#define WCH 16           // chars per word
#define EDIM 256
#define HDIM 512
#define G4 2048          // 4*H word-gate width
#define CH 1024          // char hidden (2H)
#define CG 4096          // 4*CH char-gate width
#define NCLS 20

typedef __attribute__((ext_vector_type(4))) float f32x4;
typedef __attribute__((ext_vector_type(8))) short s16x8;

__device__ __forceinline__ ushort f2b(float f){
  uint32_t u = __float_as_uint(f);
  return (ushort)((u + 0x7FFFu + ((u>>16)&1u)) >> 16);
}
__device__ __forceinline__ float b2f(ushort s){ return __uint_as_float(((uint32_t)s)<<16); }
__device__ __forceinline__ float sigf(float x){ return 1.f/(1.f+__expf(-x)); }
__device__ __forceinline__ float tanhf_(float x){
  float t = fminf(fmaxf(2.f*x,-30.f),30.f);
  float e = __expf(t);
  return (e-1.f)/(e+1.f);
}

__device__ __forceinline__ void gl16(const ushort* g, ushort* l){
  __builtin_amdgcn_global_load_lds((const __attribute__((address_space(1))) uint32_t*)g,
                                   (__attribute__((address_space(3))) uint32_t*)l, 16, 0, 0);
}

// ---------- utility ----------
__global__ void k_fill(uint32_t* __restrict__ p, uint32_t v, int n){
  int i = blockIdx.x*256 + threadIdx.x;
  if (i < n) p[i] = v;
}

__global__ void k_cvt(const float* __restrict__ s, ushort* __restrict__ d, int n){
  int i = blockIdx.x*256 + threadIdx.x;
  if (i < n) d[i] = f2b(s[i]);
}

// permute c_Whh rows: dst row dr = nb*128 + g*32 + wn*16 + hl  <-  src row g*1024 + (nb*32+wn*16+hl)
__global__ void k_cwhhp(const float* __restrict__ s, ushort* __restrict__ d){
  int i = blockIdx.x*256 + threadIdx.x;           // over 4096*1024
  int dr = i >> 10, k = i & 1023;
  int nb = dr >> 7, w7 = dr & 127;
  int g = w7 >> 5, wn = (w7>>4)&1, hl = w7&15;
  int h = nb*32 + wn*16 + hl;
  d[i] = f2b(s[(size_t)(g*1024 + h)*1024 + k]);
}

__global__ void k_emb(const int* __restrict__ words, const float* __restrict__ we,
                      ushort* __restrict__ d){
  int i = blockIdx.x*256 + threadIdx.x;           // NW*EDIM
  int w = i >> 8, e = i & 255;
  d[i] = f2b(we[(size_t)words[w]*EDIM + e]);
}

// char_proj[c][perm_col] = c_b[j] + char_emb[c] . c_Wih[j]   (perm layout as k_cwhhp)
__global__ void k_cproj(const float* __restrict__ cemb, const float* __restrict__ cwih,
                        const float* __restrict__ cb, float* __restrict__ out){
  int i = blockIdx.x*256 + threadIdx.x;           // 128*4096
  int c = i >> 12, p = i & 4095;
  int nb = p >> 7, w7 = p & 127;
  int g = w7>>5, wn = (w7>>4)&1, hl = w7&15;
  int j = g*1024 + nb*32 + wn*16 + hl;
  const float* a = cemb + (size_t)c*EDIM;
  const float* b = cwih + (size_t)j*EDIM;
  float acc = cb[j];
  for (int k=0;k<EDIM;k+=4){
    float4 av = *(const float4*)&a[k]; float4 bv = *(const float4*)&b[k];
    acc += av.x*bv.x + av.y*bv.y + av.z*bv.z + av.w*bv.w;
  }
  out[i] = acc;
}

__global__ void k_hist(const int* __restrict__ wn, const int* __restrict__ cl,
                       int* __restrict__ cnt17){
  int w = blockIdx.x*256 + threadIdx.x; if (w >= NW) return;
  int b = w >> 7, s = w & 127;
  if (s < wn[b]) atomicAdd(&cnt17[cl[w]], 1);   // cl in [1,16]
}

__global__ void k_scan(const int* __restrict__ cnt17, int* __restrict__ cnt_step,
                       int* __restrict__ cur){
  if (threadIdx.x==0 && blockIdx.x==0){
    cnt_step[16] = 0;
    for (int t=15;t>=0;t--) cnt_step[t] = cnt_step[t+1] + cnt17[t+1];
    for (int l=1;l<=16;l++) cur[l] = cnt_step[l];   // bucket cursors (len descending order)
  }
}

__global__ void k_scatter(const int* __restrict__ wn, const int* __restrict__ cl,
                          const int* __restrict__ chars, int* __restrict__ cur,
                          int* __restrict__ inv, int* __restrict__ chperm){
  int w = blockIdx.x*256 + threadIdx.x; if (w >= NW) return;
  int b = w >> 7, s = w & 127;
  if (s < wn[b]){
    int len = cl[w];
    int pos = atomicAdd(&cur[len], 1);
    inv[w] = pos;
    for (int j=0;j<WCH;j++) chperm[pos*WCH + j] = chars[w*WCH + j];
  }
}

// ---------- MFMA GEMM: C = A[M,K] @ B[N,K]^T, bf16 in, fp32 acc ----------
// EPI=0: X projection (out bf16 = acc + bias[col]), grid (M/128, N/128, ndir)
// EPI=1: char-LSTM step epilogue (gate fusion), grid (64, 32, 1)
template<int EPI>
__global__ __launch_bounds__(256) void k_gemm(
    const ushort* __restrict__ A, int ldA,
    const ushort* __restrict__ Bm, int ldB, size_t bStrideZ,
    ushort* __restrict__ outX, const float* __restrict__ bias,
    size_t oStrideZ, size_t biasStrideZ, int K,
    const int* __restrict__ cnt_step, int tstep,
    const int* __restrict__ chperm, const float* __restrict__ cproj,
    float* __restrict__ ccell, ushort* __restrict__ hcdst)
{
  int cntv = 0;
  if (EPI==1){ cntv = cnt_step[tstep]; if ((int)(blockIdx.x*128) >= cntv) return; }
  __shared__ __align__(16) ushort As[128*64];
  __shared__ __align__(16) ushort Bs[128*64];
  int tid = threadIdx.x, wid = tid>>6, lane = tid&63;
  int wm = wid>>1, wn = wid&1;
  int l15 = lane&15, l4 = lane>>4;
  const ushort* Ab = A + (size_t)blockIdx.x*128*ldA;
  const ushort* Bb = Bm + (size_t)blockIdx.z*bStrideZ + (size_t)blockIdx.y*128*ldB;
  f32x4 acc[4][4];
  #pragma unroll
  for (int i=0;i<4;i++)
    #pragma unroll
    for (int j=0;j<4;j++) acc[i][j] = f32x4{0.f,0.f,0.f,0.f};

  for (int k0=0; k0<K; k0+=64){
    // stage A and B tiles; LDS dest linear per-wave, global source pre-swizzled:
    // LDS 16B-slot cp of row holds global chunk c = cp ^ (row&7)
    #pragma unroll
    for (int i=0;i<4;i++){
      int fcb = (i*4 + wid)*64;
      int fc = fcb + lane;
      int row = fc>>3, cp = fc&7, c = cp ^ (row&7);
      gl16(Ab + (size_t)row*ldA + k0 + c*8, As + fcb*8);
    }
    #pragma unroll
    for (int i=0;i<4;i++){
      int fcb = (i*4 + wid)*64;
      int fc = fcb + lane;
      int row = fc>>3, cp = fc&7, c = cp ^ (row&7);
      gl16(Bb + (size_t)row*ldB + k0 + c*8, Bs + fcb*8);
    }
    __syncthreads();
    #pragma unroll
    for (int kw=0; kw<2; kw++){
      s16x8 af[4], bfr[4];
      #pragma unroll
      for (int mf=0; mf<4; mf++){
        int r = wm*64 + mf*16 + l15;
        int slot = (kw*4 + l4) ^ (r&7);
        af[mf] = *(const s16x8*)&As[r*64 + slot*8];
      }
      #pragma unroll
      for (int nf=0; nf<4; nf++){
        int r = (EPI==1) ? (nf*32 + wn*16 + l15) : (wn*64 + nf*16 + l15);
        int slot = (kw*4 + l4) ^ (r&7);
        bfr[nf] = *(const s16x8*)&Bs[r*64 + slot*8];
      }
      #pragma unroll
      for (int mf=0; mf<4; mf++)
        #pragma unroll
        for (int nf=0; nf<4; nf++)
          acc[mf][nf] = __builtin_amdgcn_mfma_f32_16x16x32_bf16(af[mf], bfr[nf], acc[mf][nf], 0,0,0);
    }
    __syncthreads();
  }

  if (EPI==0){
    ushort* op = outX + blockIdx.z*oStrideZ;
    const float* bp = bias + blockIdx.z*biasStrideZ;
    #pragma unroll
    for (int mf=0; mf<4; mf++){
      #pragma unroll
      for (int r=0;r<4;r++){
        int row = blockIdx.x*128 + wm*64 + mf*16 + l4*4 + r;
        #pragma unroll
        for (int nf=0;nf<4;nf++){
          int col = blockIdx.y*128 + wn*64 + nf*16 + l15;
          op[(size_t)row*G4 + col] = f2b(acc[mf][nf][r] + bp[col]);
        }
      }
    }
  } else {
    int hb = blockIdx.y*32 + wn*16 + l15;     // h index in [0,1024)
    #pragma unroll
    for (int mf=0; mf<4; mf++){
      #pragma unroll
      for (int r=0;r<4;r++){
        int row = blockIdx.x*128 + wm*64 + mf*16 + l4*4 + r;
        if (row < cntv){
          int cid = chperm[row*WCH + tstep];
          const float* cp = cproj + (size_t)cid*CG + blockIdx.y*128 + wn*16 + l15;
          float zi = acc[mf][0][r] + cp[0];
          float zf = acc[mf][1][r] + cp[32];
          float zg = acc[mf][2][r] + cp[64];
          float zo = acc[mf][3][r] + cp[96];
          size_t ix = (size_t)row*CH + hb;
          float c = ccell[ix];
          float cn = sigf(zf)*c + sigf(zi)*tanhf_(zg);
          ccell[ix] = cn;
          hcdst[ix] = f2b(sigf(zo)*tanhf_(cn));
        }
      }
    }
  }
}

// ---------- word-path LSTM step (fwd+bwd fused), fp32, TRANSPOSED state ----------
// state layout: h,c as [2][HDIM][64]  (h-index major, batch minor -> coalesced lanes)
// grid 512: blocks [0,256)=fwd, [256,512)=bwd ; each block owns 2 h-indices (8 gate cols)
__global__ __launch_bounds__(256) void k_step(
    const ushort* __restrict__ X,       // [2][NW][G4] bf16 (x@Wih^T + b)
    const float* __restrict__ Whh,      // [2][G4][HDIM]
    const float* __restrict__ hsrc,     // [2][HDIM][64] transposed
    float* __restrict__ hdst,
    float* __restrict__ cst,            // [2][HDIM][64] transposed
    const int* __restrict__ lens,
    ushort* __restrict__ outcat,        // [NW][1024] bf16
    int t)
{
  __shared__ float zsh[8][64];
  int tid = threadIdx.x;
  int dir = blockIdx.x >> 8;
  int nb  = blockIdx.x & 255;
  int h0 = nb*2;
  int zc = tid>>5, bl = tid&31;
  int hl = zc>>2, gate = zc&3;
  int j = gate*HDIM + h0 + hl;
  const float* wr = Whh + ((size_t)dir*G4 + j)*HDIM;
  const float* hT = hsrc + (size_t)dir*HDIM*64;   // [512][64]
  float a0=0.f, a1=0.f;
  #pragma unroll 4
  for (int k=0;k<HDIM;k+=4){
    float4 w = *(const float4*)&wr[k];
    const float* hp = hT + (size_t)k*64 + bl;
    // h[k..k+3][bl] : consecutive lanes -> consecutive addresses (coalesced)
    a0 += w.x*hp[0]  + w.y*hp[64]  + w.z*hp[128] + w.w*hp[192];
    a1 += w.x*hp[32] + w.y*hp[96]  + w.z*hp[160] + w.w*hp[224];
  }
  {
    int len = lens[bl];
    if (t < len){
      int pos = dir ? (len-1-t) : t;
      a0 += b2f(X[((size_t)dir*NW + bl*SLEN + pos)*G4 + j]);
    }
    int len2 = lens[bl+32];
    if (t < len2){
      int pos = dir ? (len2-1-t) : t;
      a1 += b2f(X[((size_t)dir*NW + (bl+32)*SLEN + pos)*G4 + j]);
    }
  }
  zsh[zc][bl] = a0;
  zsh[zc][bl+32] = a1;
  __syncthreads();
  if (tid < 128){
    int hl2 = tid>>6, b = tid&63;
    int hidx = h0 + hl2;
    size_t six = ((size_t)dir*HDIM + hidx)*64 + b;   // transposed index, b in lanes
    int len = lens[b];
    float hv = hsrc[six];
    if (t < len){
      float zi = zsh[hl2*4+0][b], zf = zsh[hl2*4+1][b];
      float zg = zsh[hl2*4+2][b], zo = zsh[hl2*4+3][b];
      float c = cst[six];
      float cn = sigf(zf)*c + sigf(zi)*tanhf_(zg);
      cst[six] = cn;
      hv = sigf(zo)*tanhf_(cn);
      int pos = dir ? (len-1-t) : t;
      outcat[((size_t)b*SLEN + pos)*1024 + dir*HDIM + hidx] = f2b(hv);
    }
    hdst[six] = hv;   // carry frozen state forward
  }
}

// ---------- gather final char h into word order (zeros for invalid words) ----------
__global__ void k_gather(const ushort* __restrict__ hc0, const ushort* __restrict__ hc1,
                         const int* __restrict__ inv, const int* __restrict__ cl,
                         ushort* __restrict__ ycat){
  int i = blockIdx.x*256 + threadIdx.x;     // over NW*128 (16B each)
  if (i >= NW*128) return;
  int w = i >> 7, seg = i & 127;
  int iv = inv[w];
  ulonglong2 z; z.x = 0; z.y = 0;
  if (iv >= 0){
    const ushort* src = (((cl[w]-1)&1) ? hc0 : hc1) + (size_t)iv*CH + seg*8;
    z = *(const ulonglong2*)src;
  }
  *(ulonglong2*)(ycat + (size_t)w*CH + seg*8) = z;
}

// ---------- final linear ----------
__global__ __launch_bounds__(256) void k_final(
    const ushort* __restrict__ h1cat, const ushort* __restrict__ ycat,
    const float* __restrict__ lw, const float* __restrict__ lb,
    float* __restrict__ out)
{
  int i = blockIdx.x*256 + threadIdx.x;
  if (i >= NW*NCLS) return;
  int w = i / NCLS, o = i - w*NCLS;
  const ushort* hr = h1cat + (size_t)w*1024;
  const ushort* yr = ycat  + (size_t)w*1024;
  const float* wr = lw + (size_t)o*1024;
  float acc = lb[o];
  for (int k=0;k<1024;k+=4){
    float4 wv = *(const float4*)&wr[k];
    ushort4 a4 = *(const ushort4*)&hr[k];
    ushort4 b4 = *(const ushort4*)&yr[k];
    acc += (b2f(a4.x)+b2f(b4.x))*wv.x + (b2f(a4.y)+b2f(b4.y))*wv.y
         + (b2f(a4.z)+b2f(b4.z))*wv.z + (b2f(a4.w)+b2f(b4.w))*wv.w;
  }
  out[i] = acc;
}

extern "C" void kernel_launch(void* const* d_in, const int* in_sizes, int n_in,
                              void* d_out, int out_size, void* d_ws, size_t ws_size,
                              hipStream_t stream)
{
  const int*   words = (const int*)d_in[0];
  const int*   wnum  = (const int*)d_in[1];
  const int*   chars = (const int*)d_in[2];
  const int*   clens = (const int*)d_in[3];
  const float* wemb  = (const float*)d_in[4];
  const float* cemb  = (const float*)d_in[5];
  const float* l0Wih = (const float*)d_in[6];
  const float* l0Whh = (const float*)d_in[7];
  const float* l0b   = (const float*)d_in[8];
  const float* l1Wih = (const float*)d_in[9];
  const float* l1Whh = (const float*)d_in[10];
  const float* l1b   = (const float*)d_in[11];
  const float* cWih  = (const float*)d_in[12];
  const float* cWhh  = (const float*)d_in[13];
  const float* cb    = (const float*)d_in[14];
  const float* linW  = (const float*)d_in[15];
  const float* linb  = (const float*)d_in[16];
  float* out = (float*)d_out;

  // ---- static workspace layout (peak ~111 MB); char phase aliases word phase ----
  char* base = (char*)d_ws;
  const size_t MB = (size_t)1<<20;
  ushort* hc0    = (ushort*)(base);            // 16 MB (char)  | X region (word)
  ushort* hc1    = (ushort*)(base + 16*MB);    // 16 MB (char)  |
  float*  ccell  = (float*) (base + 32*MB);    // 32 MB (char)  |
  ushort* X      = (ushort*)(base);            // 64 MB (word)
  ushort* cwp    = (ushort*)(base + 64*MB);    //  8 MB (char)  | l1w 8MB (word)
  ushort* l1w    = (ushort*)(base + 64*MB);
  float*  cproj  = (float*) (base + 72*MB);    //  2 MB (char)  | embw 4MB (word)
  int*    chperm = (int*)   (base + 74*MB);    // 512 KB (char) |
  ushort* embw   = (ushort*)(base + 72*MB);
  ushort* ycat   = (ushort*)(base + 76*MB);    // 16 MB persistent
  ushort* h0cat  = (ushort*)(base + 92*MB);    // 16 MB (layer0 out) | h1cat after X1 GEMM
  ushort* h1cat  = (ushort*)(base + 92*MB);
  ushort* l0w    = (ushort*)(base + 108*MB);   //  2 MB
  float*  hstA   = (float*) (base + 110*MB);               // 256 KB
  float*  hstB   = (float*) (base + 110*MB + 256*1024);    // 256 KB
  float*  cstw   = (float*) (base + 110*MB + 512*1024);    // 256 KB
  int*    inv    = (int*)   (base + 110*MB + 768*1024);    // 32 KB
  int*    cnt17  = (int*)   (base + 110*MB + 800*1024);    // 68 B
  int*    cntstep= (int*)   (base + 110*MB + 801*1024);    // 68 B
  int*    cur    = (int*)   (base + 110*MB + 802*1024);    // 68 B

  // ---- phase 0: char-path prep ----
  k_fill<<<1, 256, 0, stream>>>((uint32_t*)cnt17, 0u, 17);
  k_fill<<<(NW+255)/256, 256, 0, stream>>>((uint32_t*)inv, 0xFFFFFFFFu, NW);
  k_fill<<<(NW*CH/2+255)/256, 256, 0, stream>>>((uint32_t*)hc0, 0u, NW*CH/2);
  k_fill<<<(NW*CH+255)/256, 256, 0, stream>>>((uint32_t*)ccell, 0u, NW*CH);
  k_cwhhp<<<(CG*CH)/256, 256, 0, stream>>>(cWhh, cwp);
  k_cproj<<<(128*CG)/256, 256, 0, stream>>>(cemb, cWih, cb, cproj);
  k_hist<<<NW/256, 256, 0, stream>>>(wnum, clens, cnt17);
  k_scan<<<1, 1, 0, stream>>>(cnt17, cntstep, cur);
  k_scatter<<<NW/256, 256, 0, stream>>>(wnum, clens, chars, cur, inv, chperm);

  // ---- phase 1: char LSTM, 16 fused GEMM+gate steps over len-sorted valid words ----
  for (int t=0;t<WCH;t++){
    const ushort* hs = (t&1)? hc1 : hc0;
    ushort*       hd = (t&1)? hc0 : hc1;
    k_gemm<1><<<dim3(64,32,1), 256, 0, stream>>>(hs, CH, cwp, CH, 0,
        nullptr, nullptr, 0, 0, CH,
        cntstep, t, chperm, cproj, ccell, hd);
  }
  // ---- phase 2: gather final char h to word order; frees the 64MB char region ----
  k_gather<<<(NW*128+255)/256, 256, 0, stream>>>(hc0, hc1, inv, clens, ycat);

  // ---- phase 3: word path ----
  k_cvt<<<(2*G4*EDIM+255)/256, 256, 0, stream>>>(l0Wih, l0w, 2*G4*EDIM);
  k_cvt<<<(2*G4*1024+255)/256, 256, 0, stream>>>(l1Wih, l1w, 2*G4*1024);
  k_emb<<<(NW*EDIM)/256, 256, 0, stream>>>(words, wemb, embw);
  k_fill<<<(NW*512+255)/256, 256, 0, stream>>>((uint32_t*)h0cat, 0u, NW*512);
  k_fill<<<(65536+255)/256, 256, 0, stream>>>((uint32_t*)hstA, 0u, 65536);
  k_fill<<<(65536+255)/256, 256, 0, stream>>>((uint32_t*)cstw, 0u, 65536);

  // X0 = emb @ l0_Wih^T + b  (both dirs)
  k_gemm<0><<<dim3(64,16,2), 256, 0, stream>>>(embw, EDIM, l0w, EDIM, (size_t)G4*EDIM,
      X, l0b, (size_t)NW*G4, (size_t)G4, EDIM,
      nullptr, 0, nullptr, nullptr, nullptr, nullptr);

  for (int t=0;t<SLEN;t++){
    const float* hs = (t&1)? hstB : hstA;
    float*       hd = (t&1)? hstA : hstB;
    k_step<<<512, 256, 0, stream>>>(X, l0Whh, hs, hd, cstw, wnum, h0cat, t);
  }

  k_fill<<<(65536+255)/256, 256, 0, stream>>>((uint32_t*)hstA, 0u, 65536);
  k_fill<<<(65536+255)/256, 256, 0, stream>>>((uint32_t*)cstw, 0u, 65536);

  // X1 = h0cat @ l1_Wih^T + b   (fully consumes h0cat; h1cat aliases it afterwards)
  k_gemm<0><<<dim3(64,16,2), 256, 0, stream>>>(h0cat, 1024, l1w, 1024, (size_t)G4*1024,
      X, l1b, (size_t)NW*G4, (size_t)G4, 1024,
      nullptr, 0, nullptr, nullptr, nullptr, nullptr);

  k_fill<<<(NW*512+255)/256, 256, 0, stream>>>((uint32_t*)h1cat, 0u, NW*512);

  for (int t=0;t<SLEN;t++){
    const float* hs = (t&1)? hstB : hstA;
    float*       hd = (t&1)? hstA : hstB;
    k_step<<<512, 256, 0, stream>>>(X, l1Whh, hs, hd, cstw, wnum, h1cat, t);
  }

  k_final<<<(NW*NCLS+255)/256, 256, 0, stream>>>(h1cat, ycat, linW, linb, out);
}

// Round 6
// 4837.090 us; speedup vs baseline: 4.1445x; 1.6564x over previous
//
#include <hip/hip_runtime.h>
#include <stdint.h>

#define SLEN 128
#define NW 8192          // B*S words
#define WCH 16           // chars per word
#define EDIM 256
#define HDIM 512
#define G4 2048          // 4*H word-gate width
#define CH 1024          // char hidden (2H)
#define CG 4096          // 4*CH char-gate width
#define NCLS 20

typedef __attribute__((ext_vector_type(4))) float f32x4;
typedef __attribute__((ext_vector_type(8))) short s16x8;

__device__ __forceinline__ ushort f2b(float f){
  uint32_t u = __float_as_uint(f);
  return (ushort)((u + 0x7FFFu + ((u>>16)&1u)) >> 16);
}
__device__ __forceinline__ float b2f(ushort s){ return __uint_as_float(((uint32_t)s)<<16); }
__device__ __forceinline__ float sigf(float x){ return 1.f/(1.f+__expf(-x)); }
__device__ __forceinline__ float tanhf_(float x){
  float t = fminf(fmaxf(2.f*x,-30.f),30.f);
  float e = __expf(t);
  return (e-1.f)/(e+1.f);
}

__device__ __forceinline__ void gl16(const ushort* g, ushort* l){
  __builtin_amdgcn_global_load_lds((const __attribute__((address_space(1))) uint32_t*)g,
                                   (__attribute__((address_space(3))) uint32_t*)l, 16, 0, 0);
}

// ---------- utility ----------
__global__ void k_fill(uint32_t* __restrict__ p, uint32_t v, int n){
  int i = blockIdx.x*256 + threadIdx.x;
  if (i < n) p[i] = v;
}

__global__ void k_cvt(const float* __restrict__ s, ushort* __restrict__ d, int n){
  int i = blockIdx.x*256 + threadIdx.x;
  if (i < n) d[i] = f2b(s[i]);
}

// permute c_Whh rows: dst row dr = nb*128 + g*32 + wn*16 + hl  <-  src row g*1024 + (nb*32+wn*16+hl)
__global__ void k_cwhhp(const float* __restrict__ s, ushort* __restrict__ d){
  int i = blockIdx.x*256 + threadIdx.x;           // over 4096*1024
  int dr = i >> 10, k = i & 1023;
  int nb = dr >> 7, w7 = dr & 127;
  int g = w7 >> 5, wn = (w7>>4)&1, hl = w7&15;
  int h = nb*32 + wn*16 + hl;
  d[i] = f2b(s[(size_t)(g*1024 + h)*1024 + k]);
}

// permute word Whh rows (per layer): [2 dirs][2048][512] fp32 -> bf16 permuted
// dst row dr = y*128 + g*32 + wn*16 + hl  <-  src row g*512 + (y*32+wn*16+hl)
__global__ void k_wwhhp(const float* __restrict__ s, ushort* __restrict__ d){
  int i = blockIdx.x*256 + threadIdx.x;           // over 2*2048*512
  int dr = i >> 9, k = i & 511;
  int dir = dr >> 11; int r = dr & 2047;
  int y = r >> 7, w7 = r & 127;
  int g = w7 >> 5, wn = (w7>>4)&1, hl = w7&15;
  int h = y*32 + wn*16 + hl;
  d[i] = f2b(s[((size_t)dir*2048 + g*512 + h)*512 + k]);
}

__global__ void k_emb(const int* __restrict__ words, const float* __restrict__ we,
                      ushort* __restrict__ d){
  int i = blockIdx.x*256 + threadIdx.x;           // NW*EDIM
  int w = i >> 8, e = i & 255;
  d[i] = f2b(we[(size_t)words[w]*EDIM + e]);
}

// char_proj[c][perm_col] = c_b[j] + char_emb[c] . c_Wih[j]   (perm layout as k_cwhhp)
__global__ void k_cproj(const float* __restrict__ cemb, const float* __restrict__ cwih,
                        const float* __restrict__ cb, float* __restrict__ out){
  int i = blockIdx.x*256 + threadIdx.x;           // 128*4096
  int c = i >> 12, p = i & 4095;
  int nb = p >> 7, w7 = p & 127;
  int g = w7>>5, wn = (w7>>4)&1, hl = w7&15;
  int j = g*1024 + nb*32 + wn*16 + hl;
  const float* a = cemb + (size_t)c*EDIM;
  const float* b = cwih + (size_t)j*EDIM;
  float acc = cb[j];
  for (int k=0;k<EDIM;k+=4){
    float4 av = *(const float4*)&a[k]; float4 bv = *(const float4*)&b[k];
    acc += av.x*bv.x + av.y*bv.y + av.z*bv.z + av.w*bv.w;
  }
  out[i] = acc;
}

__global__ void k_hist(const int* __restrict__ wn, const int* __restrict__ cl,
                       int* __restrict__ cnt17){
  int w = blockIdx.x*256 + threadIdx.x; if (w >= NW) return;
  int b = w >> 7, s = w & 127;
  if (s < wn[b]) atomicAdd(&cnt17[cl[w]], 1);   // cl in [1,16]
}

__global__ void k_scan(const int* __restrict__ cnt17, int* __restrict__ cnt_step,
                       int* __restrict__ cur){
  if (threadIdx.x==0 && blockIdx.x==0){
    cnt_step[16] = 0;
    for (int t=15;t>=0;t--) cnt_step[t] = cnt_step[t+1] + cnt17[t+1];
    for (int l=1;l<=16;l++) cur[l] = cnt_step[l];   // bucket cursors (len descending order)
  }
}

__global__ void k_scatter(const int* __restrict__ wn, const int* __restrict__ cl,
                          const int* __restrict__ chars, int* __restrict__ cur,
                          int* __restrict__ inv, int* __restrict__ chperm){
  int w = blockIdx.x*256 + threadIdx.x; if (w >= NW) return;
  int b = w >> 7, s = w & 127;
  if (s < wn[b]){
    int len = cl[w];
    int pos = atomicAdd(&cur[len], 1);
    inv[w] = pos;
    for (int j=0;j<WCH;j++) chperm[pos*WCH + j] = chars[w*WCH + j];
  }
}

// ---------- MFMA GEMM: C = A[M,K] @ B[N,K]^T, bf16 in, fp32 acc ----------
// EPI=0: X projection (out bf16 = acc + bias[col]), grid (M/128, N/128, ndir)
// EPI=1: char-LSTM step epilogue (gate fusion), grid (64, 32, 1)
template<int EPI>
__global__ __launch_bounds__(256) void k_gemm(
    const ushort* __restrict__ A, int ldA,
    const ushort* __restrict__ Bm, int ldB, size_t bStrideZ,
    ushort* __restrict__ outX, const float* __restrict__ bias,
    size_t oStrideZ, size_t biasStrideZ, int K,
    const int* __restrict__ cnt_step, int tstep,
    const int* __restrict__ chperm, const float* __restrict__ cproj,
    float* __restrict__ ccell, ushort* __restrict__ hcdst)
{
  int cntv = 0;
  if (EPI==1){ cntv = cnt_step[tstep]; if ((int)(blockIdx.x*128) >= cntv) return; }
  __shared__ __align__(16) ushort As[128*64];
  __shared__ __align__(16) ushort Bs[128*64];
  int tid = threadIdx.x, wid = tid>>6, lane = tid&63;
  int wm = wid>>1, wn = wid&1;
  int l15 = lane&15, l4 = lane>>4;
  const ushort* Ab = A + (size_t)blockIdx.x*128*ldA;
  const ushort* Bb = Bm + (size_t)blockIdx.z*bStrideZ + (size_t)blockIdx.y*128*ldB;
  f32x4 acc[4][4];
  #pragma unroll
  for (int i=0;i<4;i++)
    #pragma unroll
    for (int j=0;j<4;j++) acc[i][j] = f32x4{0.f,0.f,0.f,0.f};

  for (int k0=0; k0<K; k0+=64){
    // stage A and B tiles; LDS dest linear per-wave, global source pre-swizzled:
    // LDS 16B-slot cp of row holds global chunk c = cp ^ (row&7)
    #pragma unroll
    for (int i=0;i<4;i++){
      int fcb = (i*4 + wid)*64;
      int fc = fcb + lane;
      int row = fc>>3, cp = fc&7, c = cp ^ (row&7);
      gl16(Ab + (size_t)row*ldA + k0 + c*8, As + fcb*8);
    }
    #pragma unroll
    for (int i=0;i<4;i++){
      int fcb = (i*4 + wid)*64;
      int fc = fcb + lane;
      int row = fc>>3, cp = fc&7, c = cp ^ (row&7);
      gl16(Bb + (size_t)row*ldB + k0 + c*8, Bs + fcb*8);
    }
    __syncthreads();
    #pragma unroll
    for (int kw=0; kw<2; kw++){
      s16x8 af[4], bfr[4];
      #pragma unroll
      for (int mf=0; mf<4; mf++){
        int r = wm*64 + mf*16 + l15;
        int slot = (kw*4 + l4) ^ (r&7);
        af[mf] = *(const s16x8*)&As[r*64 + slot*8];
      }
      #pragma unroll
      for (int nf=0; nf<4; nf++){
        int r = (EPI==1) ? (nf*32 + wn*16 + l15) : (wn*64 + nf*16 + l15);
        int slot = (kw*4 + l4) ^ (r&7);
        bfr[nf] = *(const s16x8*)&Bs[r*64 + slot*8];
      }
      #pragma unroll
      for (int mf=0; mf<4; mf++)
        #pragma unroll
        for (int nf=0; nf<4; nf++)
          acc[mf][nf] = __builtin_amdgcn_mfma_f32_16x16x32_bf16(af[mf], bfr[nf], acc[mf][nf], 0,0,0);
    }
    __syncthreads();
  }

  if (EPI==0){
    ushort* op = outX + blockIdx.z*oStrideZ;
    const float* bp = bias + blockIdx.z*biasStrideZ;
    #pragma unroll
    for (int mf=0; mf<4; mf++){
      #pragma unroll
      for (int r=0;r<4;r++){
        int row = blockIdx.x*128 + wm*64 + mf*16 + l4*4 + r;
        #pragma unroll
        for (int nf=0;nf<4;nf++){
          int col = blockIdx.y*128 + wn*64 + nf*16 + l15;
          op[(size_t)row*G4 + col] = f2b(acc[mf][nf][r] + bp[col]);
        }
      }
    }
  } else {
    int hb = blockIdx.y*32 + wn*16 + l15;     // h index in [0,1024)
    #pragma unroll
    for (int mf=0; mf<4; mf++){
      #pragma unroll
      for (int r=0;r<4;r++){
        int row = blockIdx.x*128 + wm*64 + mf*16 + l4*4 + r;
        if (row < cntv){
          int cid = chperm[row*WCH + tstep];
          const float* cp = cproj + (size_t)cid*CG + blockIdx.y*128 + wn*16 + l15;
          float zi = acc[mf][0][r] + cp[0];
          float zf = acc[mf][1][r] + cp[32];
          float zg = acc[mf][2][r] + cp[64];
          float zo = acc[mf][3][r] + cp[96];
          size_t ix = (size_t)row*CH + hb;
          float c = ccell[ix];
          float cn = sigf(zf)*c + sigf(zi)*tanhf_(zg);
          ccell[ix] = cn;
          hcdst[ix] = f2b(sigf(zo)*tanhf_(cn));
        }
      }
    }
  }
}

// ---------- word-path LSTM step via MFMA (fwd+bwd fused) ----------
// h state: [2][64][512] bf16 (A-operand layout), c: [2][512][64] fp32
// Wp: [2][2048][512] bf16, rows permuted dr = y*128 + g*32 + wn*16 + hl
// grid (16, 2): blockIdx.x = h-block y, blockIdx.y = dir. 256 threads.
// Per block: z tile [64 batch x 128 perm gate cols] = h @ Wp_slice^T, gate-fused epilogue.
__global__ __launch_bounds__(256) void k_wstep(
    const ushort* __restrict__ hsrc,
    ushort* __restrict__ hdst,
    float* __restrict__ cst,
    const ushort* __restrict__ X,       // [2][NW][G4] bf16 (x@Wih^T + b)
    const ushort* __restrict__ Wp,
    const int* __restrict__ lens,
    ushort* __restrict__ outcat,        // [NW][1024] bf16
    int t)
{
  __shared__ __align__(16) ushort As[64*64];
  __shared__ __align__(16) ushort Bs[128*64];
  int tid = threadIdx.x, wid = tid>>6, lane = tid&63;
  int l15 = lane&15, l4 = lane>>4;
  int y = blockIdx.x;
  int dir = blockIdx.y;
  const ushort* Ab = hsrc + (size_t)dir*64*512;
  const ushort* Bb = Wp + ((size_t)dir*2048 + (size_t)y*128)*512;
  f32x4 acc[8];
  #pragma unroll
  for (int n=0;n<8;n++) acc[n] = f32x4{0.f,0.f,0.f,0.f};

  for (int k0=0; k0<512; k0+=64){
    #pragma unroll
    for (int i=0;i<2;i++){          // A: 64x64 -> 512 chunks
      int fcb = (i*4 + wid)*64;
      int fc = fcb + lane;
      int row = fc>>3, cp = fc&7, c = cp ^ (row&7);
      gl16(Ab + (size_t)row*512 + k0 + c*8, As + fcb*8);
    }
    #pragma unroll
    for (int i=0;i<4;i++){          // B: 128x64 -> 1024 chunks
      int fcb = (i*4 + wid)*64;
      int fc = fcb + lane;
      int row = fc>>3, cp = fc&7, c = cp ^ (row&7);
      gl16(Bb + (size_t)row*512 + k0 + c*8, Bs + fcb*8);
    }
    __syncthreads();
    #pragma unroll
    for (int kw=0; kw<2; kw++){
      s16x8 af;
      {
        int r = wid*16 + l15;
        int slot = (kw*4 + l4) ^ (r&7);
        af = *(const s16x8*)&As[r*64 + slot*8];
      }
      #pragma unroll
      for (int nf=0; nf<8; nf++){
        int r = nf*16 + l15;
        int slot = (kw*4 + l4) ^ (r&7);
        s16x8 bfr = *(const s16x8*)&Bs[r*64 + slot*8];
        acc[nf] = __builtin_amdgcn_mfma_f32_16x16x32_bf16(af, bfr, acc[nf], 0,0,0);
      }
    }
    __syncthreads();
  }

  // epilogue: rows b = wid*16 + l4*4 + r; cols: nf = 2*gate + wn, h = y*32+wn*16+l15
  int b0 = wid*16 + l4*4;
  int lenv[4], posv[4];
  #pragma unroll
  for (int r=0;r<4;r++){
    int len = lens[b0+r];
    lenv[r] = len;
    posv[r] = dir ? (len-1-t) : t;
  }
  #pragma unroll
  for (int wn=0;wn<2;wn++){
    int h = y*32 + wn*16 + l15;
    #pragma unroll
    for (int r=0;r<4;r++){
      int b = b0 + r;
      size_t hix = ((size_t)dir*64 + b)*512 + h;
      ushort hnew;
      if (t < lenv[r]){
        size_t xbase = ((size_t)dir*NW + (size_t)b*SLEN + posv[r])*G4 + h;
        float zi = acc[0+wn][r] + b2f(X[xbase]);
        float zf = acc[2+wn][r] + b2f(X[xbase + 512]);
        float zg = acc[4+wn][r] + b2f(X[xbase + 1024]);
        float zo = acc[6+wn][r] + b2f(X[xbase + 1536]);
        size_t cix = ((size_t)dir*512 + h)*64 + b;
        float c = cst[cix];
        float cn = sigf(zf)*c + sigf(zi)*tanhf_(zg);
        cst[cix] = cn;
        float hv = sigf(zo)*tanhf_(cn);
        hnew = f2b(hv);
        outcat[((size_t)b*SLEN + posv[r])*1024 + dir*HDIM + h] = hnew;
      } else {
        hnew = hsrc[hix];
      }
      hdst[hix] = hnew;
    }
  }
}

// ---------- gather final char h into word order (zeros for invalid words) ----------
__global__ void k_gather(const ushort* __restrict__ hc0, const ushort* __restrict__ hc1,
                         const int* __restrict__ inv, const int* __restrict__ cl,
                         ushort* __restrict__ ycat){
  int i = blockIdx.x*256 + threadIdx.x;     // over NW*128 (16B each)
  if (i >= NW*128) return;
  int w = i >> 7, seg = i & 127;
  int iv = inv[w];
  ulonglong2 z; z.x = 0; z.y = 0;
  if (iv >= 0){
    const ushort* src = (((cl[w]-1)&1) ? hc0 : hc1) + (size_t)iv*CH + seg*8;
    z = *(const ulonglong2*)src;
  }
  *(ulonglong2*)(ycat + (size_t)w*CH + seg*8) = z;
}

// ---------- final linear ----------
__global__ __launch_bounds__(256) void k_final(
    const ushort* __restrict__ h1cat, const ushort* __restrict__ ycat,
    const float* __restrict__ lw, const float* __restrict__ lb,
    float* __restrict__ out)
{
  int i = blockIdx.x*256 + threadIdx.x;
  if (i >= NW*NCLS) return;
  int w = i / NCLS, o = i - w*NCLS;
  const ushort* hr = h1cat + (size_t)w*1024;
  const ushort* yr = ycat  + (size_t)w*1024;
  const float* wr = lw + (size_t)o*1024;
  float acc = lb[o];
  for (int k=0;k<1024;k+=4){
    float4 wv = *(const float4*)&wr[k];
    ushort4 a4 = *(const ushort4*)&hr[k];
    ushort4 b4 = *(const ushort4*)&yr[k];
    acc += (b2f(a4.x)+b2f(b4.x))*wv.x + (b2f(a4.y)+b2f(b4.y))*wv.y
         + (b2f(a4.z)+b2f(b4.z))*wv.z + (b2f(a4.w)+b2f(b4.w))*wv.w;
  }
  out[i] = acc;
}

extern "C" void kernel_launch(void* const* d_in, const int* in_sizes, int n_in,
                              void* d_out, int out_size, void* d_ws, size_t ws_size,
                              hipStream_t stream)
{
  const int*   words = (const int*)d_in[0];
  const int*   wnum  = (const int*)d_in[1];
  const int*   chars = (const int*)d_in[2];
  const int*   clens = (const int*)d_in[3];
  const float* wemb  = (const float*)d_in[4];
  const float* cemb  = (const float*)d_in[5];
  const float* l0Wih = (const float*)d_in[6];
  const float* l0Whh = (const float*)d_in[7];
  const float* l0b   = (const float*)d_in[8];
  const float* l1Wih = (const float*)d_in[9];
  const float* l1Whh = (const float*)d_in[10];
  const float* l1b   = (const float*)d_in[11];
  const float* cWih  = (const float*)d_in[12];
  const float* cWhh  = (const float*)d_in[13];
  const float* cb    = (const float*)d_in[14];
  const float* linW  = (const float*)d_in[15];
  const float* linb  = (const float*)d_in[16];
  float* out = (float*)d_out;

  // ---- static workspace layout (peak ~115 MB); char phase aliases word phase ----
  char* base = (char*)d_ws;
  const size_t MB = (size_t)1<<20;
  ushort* hc0    = (ushort*)(base);            // 16 MB (char)  | X region (word)
  ushort* hc1    = (ushort*)(base + 16*MB);    // 16 MB (char)  |
  float*  ccell  = (float*) (base + 32*MB);    // 32 MB (char)  |
  ushort* X      = (ushort*)(base);            // 64 MB (word)
  ushort* cwp    = (ushort*)(base + 64*MB);    //  8 MB (char)  | l1w 8MB (word)
  ushort* l1w    = (ushort*)(base + 64*MB);
  float*  cproj  = (float*) (base + 72*MB);    //  2 MB (char)  | embw 4MB | w1p 4MB (after X0)
  int*    chperm = (int*)   (base + 74*MB);    // 512 KB (char) |
  ushort* embw   = (ushort*)(base + 72*MB);
  ushort* w1p    = (ushort*)(base + 72*MB);
  ushort* ycat   = (ushort*)(base + 76*MB);    // 16 MB persistent
  ushort* h0cat  = (ushort*)(base + 92*MB);    // 16 MB (layer0 out) | h1cat after X1 GEMM
  ushort* h1cat  = (ushort*)(base + 92*MB);
  ushort* l0w    = (ushort*)(base + 108*MB);   //  2 MB
  ushort* w0p    = (ushort*)(base + 110*MB);   //  4 MB
  ushort* hA     = (ushort*)(base + 114*MB);                 // 128 KB [2][64][512] bf16
  ushort* hB     = (ushort*)(base + 114*MB + 128*1024);      // 128 KB
  float*  cw     = (float*) (base + 114*MB + 256*1024);      // 256 KB [2][512][64] fp32
  int*    inv    = (int*)   (base + 114*MB + 512*1024);      // 32 KB
  int*    cnt17  = (int*)   (base + 114*MB + 544*1024);      // 68 B
  int*    cntstep= (int*)   (base + 114*MB + 545*1024);      // 68 B
  int*    cur    = (int*)   (base + 114*MB + 546*1024);      // 68 B

  // ---- phase 0: char-path prep ----
  k_fill<<<1, 256, 0, stream>>>((uint32_t*)cnt17, 0u, 17);
  k_fill<<<(NW+255)/256, 256, 0, stream>>>((uint32_t*)inv, 0xFFFFFFFFu, NW);
  k_fill<<<(NW*CH/2+255)/256, 256, 0, stream>>>((uint32_t*)hc0, 0u, NW*CH/2);
  k_fill<<<(NW*CH+255)/256, 256, 0, stream>>>((uint32_t*)ccell, 0u, NW*CH);
  k_cwhhp<<<(CG*CH)/256, 256, 0, stream>>>(cWhh, cwp);
  k_cproj<<<(128*CG)/256, 256, 0, stream>>>(cemb, cWih, cb, cproj);
  k_hist<<<NW/256, 256, 0, stream>>>(wnum, clens, cnt17);
  k_scan<<<1, 1, 0, stream>>>(cnt17, cntstep, cur);
  k_scatter<<<NW/256, 256, 0, stream>>>(wnum, clens, chars, cur, inv, chperm);

  // ---- phase 1: char LSTM, 16 fused GEMM+gate steps over len-sorted valid words ----
  for (int t=0;t<WCH;t++){
    const ushort* hs = (t&1)? hc1 : hc0;
    ushort*       hd = (t&1)? hc0 : hc1;
    k_gemm<1><<<dim3(64,32,1), 256, 0, stream>>>(hs, CH, cwp, CH, 0,
        nullptr, nullptr, 0, 0, CH,
        cntstep, t, chperm, cproj, ccell, hd);
  }
  // ---- phase 2: gather final char h to word order; frees the 64MB char region ----
  k_gather<<<(NW*128+255)/256, 256, 0, stream>>>(hc0, hc1, inv, clens, ycat);

  // ---- phase 3: word path ----
  k_cvt<<<(2*G4*EDIM+255)/256, 256, 0, stream>>>(l0Wih, l0w, 2*G4*EDIM);
  k_cvt<<<(2*G4*1024+255)/256, 256, 0, stream>>>(l1Wih, l1w, 2*G4*1024);
  k_wwhhp<<<(2*G4*HDIM)/256, 256, 0, stream>>>(l0Whh, w0p);
  k_emb<<<(NW*EDIM)/256, 256, 0, stream>>>(words, wemb, embw);
  k_fill<<<(NW*512+255)/256, 256, 0, stream>>>((uint32_t*)h0cat, 0u, NW*512);
  k_fill<<<(32768+255)/256, 256, 0, stream>>>((uint32_t*)hA, 0u, 32768);
  k_fill<<<(65536+255)/256, 256, 0, stream>>>((uint32_t*)cw, 0u, 65536);

  // X0 = emb @ l0_Wih^T + b  (both dirs)
  k_gemm<0><<<dim3(64,16,2), 256, 0, stream>>>(embw, EDIM, l0w, EDIM, (size_t)G4*EDIM,
      X, l0b, (size_t)NW*G4, (size_t)G4, EDIM,
      nullptr, 0, nullptr, nullptr, nullptr, nullptr);

  // w1p overwrites embw region (embw fully consumed by X0 GEMM)
  k_wwhhp<<<(2*G4*HDIM)/256, 256, 0, stream>>>(l1Whh, w1p);

  // word layer 0 recurrence (MFMA steps)
  for (int t=0;t<SLEN;t++){
    const ushort* hs = (t&1)? hB : hA;
    ushort*       hd = (t&1)? hA : hB;
    k_wstep<<<dim3(16,2), 256, 0, stream>>>(hs, hd, cw, X, w0p, wnum, h0cat, t);
  }

  k_fill<<<(32768+255)/256, 256, 0, stream>>>((uint32_t*)hA, 0u, 32768);
  k_fill<<<(65536+255)/256, 256, 0, stream>>>((uint32_t*)cw, 0u, 65536);

  // X1 = h0cat @ l1_Wih^T + b   (fully consumes h0cat; h1cat aliases it afterwards)
  k_gemm<0><<<dim3(64,16,2), 256, 0, stream>>>(h0cat, 1024, l1w, 1024, (size_t)G4*1024,
      X, l1b, (size_t)NW*G4, (size_t)G4, 1024,
      nullptr, 0, nullptr, nullptr, nullptr, nullptr);

  k_fill<<<(NW*512+255)/256, 256, 0, stream>>>((uint32_t*)h1cat, 0u, NW*512);

  // word layer 1 recurrence
  for (int t=0;t<SLEN;t++){
    const ushort* hs = (t&1)? hB : hA;
    ushort*       hd = (t&1)? hA : hB;
    k_wstep<<<dim3(16,2), 256, 0, stream>>>(hs, hd, cw, X, w1p, wnum, h1cat, t);
  }

  k_final<<<(NW*NCLS+255)/256, 256, 0, stream>>>(h1cat, ycat, linW, linb, out);
}

// Round 7
// 4432.392 us; speedup vs baseline: 4.5229x; 1.0913x over previous
//
#include <hip/hip_runtime.h>
#include <stdint.h>

#define SLEN 128
#define NW 8192          // B*S words
#define WCH 16           // chars per word
#define EDIM 256
#define HDIM 512
#define G4 2048          // 4*H word-gate width
#define CH 1024          // char hidden (2H)
#define CG 4096          // 4*CH char-gate width
#define NCLS 20

typedef __attribute__((ext_vector_type(4))) float f32x4;
typedef __attribute__((ext_vector_type(8))) short s16x8;

__device__ __forceinline__ ushort f2b(float f){
  uint32_t u = __float_as_uint(f);
  return (ushort)((u + 0x7FFFu + ((u>>16)&1u)) >> 16);
}
__device__ __forceinline__ float b2f(ushort s){ return __uint_as_float(((uint32_t)s)<<16); }
__device__ __forceinline__ float sigf(float x){ return 1.f/(1.f+__expf(-x)); }
__device__ __forceinline__ float tanhf_(float x){
  float t = fminf(fmaxf(2.f*x,-30.f),30.f);
  float e = __expf(t);
  return (e-1.f)/(e+1.f);
}

__device__ __forceinline__ void gl16(const ushort* g, ushort* l){
  __builtin_amdgcn_global_load_lds((const __attribute__((address_space(1))) uint32_t*)g,
                                   (__attribute__((address_space(3))) uint32_t*)l, 16, 0, 0);
}

// ---------- utility ----------
__global__ void k_fill(uint32_t* __restrict__ p, uint32_t v, int n){
  int i = blockIdx.x*256 + threadIdx.x;
  if (i < n) p[i] = v;
}

__global__ void k_cvt(const float* __restrict__ s, ushort* __restrict__ d, int n){
  int i = blockIdx.x*256 + threadIdx.x;
  if (i < n) d[i] = f2b(s[i]);
}

// permute c_Whh rows: dst row dr = nb*128 + g*32 + wn*16 + hl  <-  src row g*1024 + (nb*32+wn*16+hl)
__global__ void k_cwhhp(const float* __restrict__ s, ushort* __restrict__ d){
  int i = blockIdx.x*256 + threadIdx.x;           // over 4096*1024
  int dr = i >> 10, k = i & 1023;
  int nb = dr >> 7, w7 = dr & 127;
  int g = w7 >> 5, wn = (w7>>4)&1, hl = w7&15;
  int h = nb*32 + wn*16 + hl;
  d[i] = f2b(s[(size_t)(g*1024 + h)*1024 + k]);
}

// permute word Whh rows (per layer): [2 dirs][2048][512] fp32 -> bf16 permuted
// dst row dr = y*128 + g*32 + wn*16 + hl  <-  src row g*512 + (y*32+wn*16+hl)
__global__ void k_wwhhp(const float* __restrict__ s, ushort* __restrict__ d){
  int i = blockIdx.x*256 + threadIdx.x;           // over 2*2048*512
  int dr = i >> 9, k = i & 511;
  int dir = dr >> 11; int r = dr & 2047;
  int y = r >> 7, w7 = r & 127;
  int g = w7 >> 5, wn = (w7>>4)&1, hl = w7&15;
  int h = y*32 + wn*16 + hl;
  d[i] = f2b(s[((size_t)dir*2048 + g*512 + h)*512 + k]);
}

__global__ void k_emb(const int* __restrict__ words, const float* __restrict__ we,
                      ushort* __restrict__ d){
  int i = blockIdx.x*256 + threadIdx.x;           // NW*EDIM
  int w = i >> 8, e = i & 255;
  d[i] = f2b(we[(size_t)words[w]*EDIM + e]);
}

// char_proj[c][perm_col] = c_b[j] + char_emb[c] . c_Wih[j]   (perm layout as k_cwhhp)
__global__ void k_cproj(const float* __restrict__ cemb, const float* __restrict__ cwih,
                        const float* __restrict__ cb, float* __restrict__ out){
  int i = blockIdx.x*256 + threadIdx.x;           // 128*4096
  int c = i >> 12, p = i & 4095;
  int nb = p >> 7, w7 = p & 127;
  int g = w7>>5, wn = (w7>>4)&1, hl = w7&15;
  int j = g*1024 + nb*32 + wn*16 + hl;
  const float* a = cemb + (size_t)c*EDIM;
  const float* b = cwih + (size_t)j*EDIM;
  float acc = cb[j];
  for (int k=0;k<EDIM;k+=4){
    float4 av = *(const float4*)&a[k]; float4 bv = *(const float4*)&b[k];
    acc += av.x*bv.x + av.y*bv.y + av.z*bv.z + av.w*bv.w;
  }
  out[i] = acc;
}

__global__ void k_hist(const int* __restrict__ wn, const int* __restrict__ cl,
                       int* __restrict__ cnt17){
  int w = blockIdx.x*256 + threadIdx.x; if (w >= NW) return;
  int b = w >> 7, s = w & 127;
  if (s < wn[b]) atomicAdd(&cnt17[cl[w]], 1);   // cl in [1,16]
}

__global__ void k_scan(const int* __restrict__ cnt17, int* __restrict__ cnt_step,
                       int* __restrict__ cur){
  if (threadIdx.x==0 && blockIdx.x==0){
    cnt_step[16] = 0;
    for (int t=15;t>=0;t--) cnt_step[t] = cnt_step[t+1] + cnt17[t+1];
    for (int l=1;l<=16;l++) cur[l] = cnt_step[l];   // bucket cursors (len descending order)
  }
}

__global__ void k_scatter(const int* __restrict__ wn, const int* __restrict__ cl,
                          const int* __restrict__ chars, int* __restrict__ cur,
                          int* __restrict__ inv, int* __restrict__ chperm){
  int w = blockIdx.x*256 + threadIdx.x; if (w >= NW) return;
  int b = w >> 7, s = w & 127;
  if (s < wn[b]){
    int len = cl[w];
    int pos = atomicAdd(&cur[len], 1);
    inv[w] = pos;
    for (int j=0;j<WCH;j++) chperm[pos*WCH + j] = chars[w*WCH + j];
  }
}

// ---------- MFMA GEMM: C = A[M,K] @ B[N,K]^T, bf16 in, fp32 acc ----------
// EPI=0: X projection (out bf16 = acc + bias[col]), grid (M/128, N/128, ndir)
// EPI=1: char-LSTM step epilogue (gate fusion), grid (64, 32, 1)
template<int EPI>
__global__ __launch_bounds__(256) void k_gemm(
    const ushort* __restrict__ A, int ldA,
    const ushort* __restrict__ Bm, int ldB, size_t bStrideZ,
    ushort* __restrict__ outX, const float* __restrict__ bias,
    size_t oStrideZ, size_t biasStrideZ, int K,
    const int* __restrict__ cnt_step, int tstep,
    const int* __restrict__ chperm, const float* __restrict__ cproj,
    float* __restrict__ ccell, ushort* __restrict__ hcdst)
{
  int cntv = 0;
  if (EPI==1){ cntv = cnt_step[tstep]; if ((int)(blockIdx.x*128) >= cntv) return; }
  __shared__ __align__(16) ushort As[128*64];
  __shared__ __align__(16) ushort Bs[128*64];
  int tid = threadIdx.x, wid = tid>>6, lane = tid&63;
  int wm = wid>>1, wn = wid&1;
  int l15 = lane&15, l4 = lane>>4;
  const ushort* Ab = A + (size_t)blockIdx.x*128*ldA;
  const ushort* Bb = Bm + (size_t)blockIdx.z*bStrideZ + (size_t)blockIdx.y*128*ldB;
  f32x4 acc[4][4];
  #pragma unroll
  for (int i=0;i<4;i++)
    #pragma unroll
    for (int j=0;j<4;j++) acc[i][j] = f32x4{0.f,0.f,0.f,0.f};

  for (int k0=0; k0<K; k0+=64){
    // stage A and B tiles; LDS dest linear per-wave, global source pre-swizzled:
    // LDS 16B-slot cp of row holds global chunk c = cp ^ (row&7)
    #pragma unroll
    for (int i=0;i<4;i++){
      int fcb = (i*4 + wid)*64;
      int fc = fcb + lane;
      int row = fc>>3, cp = fc&7, c = cp ^ (row&7);
      gl16(Ab + (size_t)row*ldA + k0 + c*8, As + fcb*8);
    }
    #pragma unroll
    for (int i=0;i<4;i++){
      int fcb = (i*4 + wid)*64;
      int fc = fcb + lane;
      int row = fc>>3, cp = fc&7, c = cp ^ (row&7);
      gl16(Bb + (size_t)row*ldB + k0 + c*8, Bs + fcb*8);
    }
    __syncthreads();
    #pragma unroll
    for (int kw=0; kw<2; kw++){
      s16x8 af[4], bfr[4];
      #pragma unroll
      for (int mf=0; mf<4; mf++){
        int r = wm*64 + mf*16 + l15;
        int slot = (kw*4 + l4) ^ (r&7);
        af[mf] = *(const s16x8*)&As[r*64 + slot*8];
      }
      #pragma unroll
      for (int nf=0; nf<4; nf++){
        int r = (EPI==1) ? (nf*32 + wn*16 + l15) : (wn*64 + nf*16 + l15);
        int slot = (kw*4 + l4) ^ (r&7);
        bfr[nf] = *(const s16x8*)&Bs[r*64 + slot*8];
      }
      #pragma unroll
      for (int mf=0; mf<4; mf++)
        #pragma unroll
        for (int nf=0; nf<4; nf++)
          acc[mf][nf] = __builtin_amdgcn_mfma_f32_16x16x32_bf16(af[mf], bfr[nf], acc[mf][nf], 0,0,0);
    }
    __syncthreads();
  }

  if (EPI==0){
    ushort* op = outX + blockIdx.z*oStrideZ;
    const float* bp = bias + blockIdx.z*biasStrideZ;
    #pragma unroll
    for (int mf=0; mf<4; mf++){
      #pragma unroll
      for (int r=0;r<4;r++){
        int row = blockIdx.x*128 + wm*64 + mf*16 + l4*4 + r;
        #pragma unroll
        for (int nf=0;nf<4;nf++){
          int col = blockIdx.y*128 + wn*64 + nf*16 + l15;
          op[(size_t)row*G4 + col] = f2b(acc[mf][nf][r] + bp[col]);
        }
      }
    }
  } else {
    int hb = blockIdx.y*32 + wn*16 + l15;     // h index in [0,1024)
    #pragma unroll
    for (int mf=0; mf<4; mf++){
      #pragma unroll
      for (int r=0;r<4;r++){
        int row = blockIdx.x*128 + wm*64 + mf*16 + l4*4 + r;
        if (row < cntv){
          int cid = chperm[row*WCH + tstep];
          const float* cp = cproj + (size_t)cid*CG + blockIdx.y*128 + wn*16 + l15;
          float zi = acc[mf][0][r] + cp[0];
          float zf = acc[mf][1][r] + cp[32];
          float zg = acc[mf][2][r] + cp[64];
          float zo = acc[mf][3][r] + cp[96];
          size_t ix = (size_t)row*CH + hb;
          float c = ccell[ix];
          float cn = sigf(zf)*c + sigf(zi)*tanhf_(zg);
          ccell[ix] = cn;
          hcdst[ix] = f2b(sigf(zo)*tanhf_(cn));
        }
      }
    }
  }
}

// ---------- persistent word-path LSTM recurrence (one launch per layer) ----------
// grid 32: bid = dir*16 + y. Block owns perm-cols [y*128, y*128+128) of its dir.
// W slice LDS-resident (128KB). h double-buffered in global hbuf[2][2][64][512] bf16.
// c-state + frozen-h carried in registers. Per-dir 16-block device-scope barrier per step.
__global__ __launch_bounds__(256) void k_wrec(
    ushort* __restrict__ hbuf,          // [2 slots][2 dirs][64][512]
    const ushort* __restrict__ X,       // [2][NW][G4] bf16 (x@Wih^T + b)
    const ushort* __restrict__ Wp,      // [2][2048][512] permuted bf16
    const int* __restrict__ lens,
    ushort* __restrict__ outcat,        // [NW][1024] bf16
    int* __restrict__ bar)              // [2] per-dir counters, zeroed before launch
{
  __shared__ __align__(16) ushort Ws[8*128*64];   // 128 KB
  __shared__ __align__(16) ushort As[64*64];      //   8 KB
  int tid = threadIdx.x, wid = tid>>6, lane = tid&63;
  int l15 = lane&15, l4 = lane>>4;
  int y = blockIdx.x & 15, dir = blockIdx.x >> 4;
  const ushort* Wb = Wp + ((size_t)dir*2048 + (size_t)y*128)*512;

  // ---- prologue: stage W slice into LDS (8 K-tiles of [128][64], swizzled like Bs) ----
  #pragma unroll
  for (int kt=0; kt<8; ++kt)
    #pragma unroll
    for (int i=0;i<4;i++){
      int fcb = (i*4 + wid)*64;
      int fc = fcb + lane;
      int row = fc>>3, cp = fc&7, c = cp ^ (row&7);
      gl16(Wb + (size_t)row*512 + kt*64 + c*8, Ws + kt*8192 + fcb*8);
    }
  asm volatile("s_waitcnt vmcnt(0)" ::: "memory");
  __builtin_amdgcn_sched_barrier(0);
  __builtin_amdgcn_s_barrier();

  int b0 = wid*16 + l4*4;
  int lenv[4];
  #pragma unroll
  for (int r=0;r<4;r++) lenv[r] = lens[b0+r];
  float  cacc[2][4];
  ushort hprev[2][4];
  #pragma unroll
  for (int wn=0;wn<2;wn++)
    #pragma unroll
    for (int r=0;r<4;r++){ cacc[wn][r]=0.f; hprev[wn][r]=0; }

  int* mybar = bar + dir;

  for (int t=0;t<SLEN;t++){
    const ushort* hsrc = hbuf + ((size_t)((t&1)*2 + dir))*32768;
    ushort*       hdst = hbuf + ((size_t)((((t&1)^1))*2 + dir))*32768;
    f32x4 acc[8];
    #pragma unroll
    for (int n=0;n<8;n++) acc[n] = f32x4{0.f,0.f,0.f,0.f};

    for (int kt=0; kt<8; ++kt){
      // stage A tile kt (h rows 64 x k 64) from coherent global
      #pragma unroll
      for (int i=0;i<2;i++){
        int fcb = (i*4 + wid)*64;
        int fc = fcb + lane;
        int row = fc>>3, cp = fc&7, c = cp ^ (row&7);
        gl16(hsrc + (size_t)row*512 + kt*64 + c*8, As + fcb*8);
      }
      asm volatile("s_waitcnt vmcnt(0)" ::: "memory");
      __builtin_amdgcn_sched_barrier(0);
      __builtin_amdgcn_s_barrier();
      #pragma unroll
      for (int kw=0; kw<2; kw++){
        s16x8 af;
        { int r = wid*16 + l15; int slot = (kw*4 + l4) ^ (r&7);
          af = *(const s16x8*)&As[r*64 + slot*8]; }
        #pragma unroll
        for (int nf=0; nf<8; nf++){
          int r = nf*16 + l15; int slot = (kw*4 + l4) ^ (r&7);
          s16x8 bfr = *(const s16x8*)&Ws[kt*8192 + r*64 + slot*8];
          acc[nf] = __builtin_amdgcn_mfma_f32_16x16x32_bf16(af, bfr, acc[nf], 0,0,0);
        }
      }
      __builtin_amdgcn_s_barrier();   // all waves done reading As before next overwrite
    }

    // ---- gate-fused epilogue (identical math to previous k_wstep) ----
    #pragma unroll
    for (int wn=0;wn<2;wn++){
      int h = y*32 + wn*16 + l15;
      #pragma unroll
      for (int r=0;r<4;r++){
        int b = b0 + r;
        ushort hnew;
        if (t < lenv[r]){
          int pos = dir ? (lenv[r]-1-t) : t;
          size_t xbase = ((size_t)dir*NW + (size_t)b*SLEN + pos)*G4 + h;
          float zi = acc[0+wn][r] + b2f(X[xbase]);
          float zf = acc[2+wn][r] + b2f(X[xbase + 512]);
          float zg = acc[4+wn][r] + b2f(X[xbase + 1024]);
          float zo = acc[6+wn][r] + b2f(X[xbase + 1536]);
          float cn = sigf(zf)*cacc[wn][r] + sigf(zi)*tanhf_(zg);
          cacc[wn][r] = cn;
          float hv = sigf(zo)*tanhf_(cn);
          hnew = f2b(hv);
          outcat[((size_t)b*SLEN + pos)*1024 + dir*HDIM + h] = hnew;
        } else {
          hnew = hprev[wn][r];
        }
        hprev[wn][r] = hnew;
        hdst[(size_t)b*512 + h] = hnew;
      }
    }

    // ---- per-dir grid barrier: release stores -> count -> acquire ----
    __syncthreads();                       // drains vmcnt: block's stores in L2
    if (tid==0){
      __threadfence();                     // agent release: L2 writeback to coherent point
      __hip_atomic_fetch_add(mybar, 1, __ATOMIC_RELEASE, __HIP_MEMORY_SCOPE_AGENT);
      int tgt = 16*(t+1);
      while (__hip_atomic_load(mybar, __ATOMIC_ACQUIRE, __HIP_MEMORY_SCOPE_AGENT) < tgt)
        __builtin_amdgcn_s_sleep(8);
      __threadfence();                     // agent acquire: invalidate L1/L2
    }
    __syncthreads();
  }
}

// ---------- gather final char h into word order (zeros for invalid words) ----------
__global__ void k_gather(const ushort* __restrict__ hc0, const ushort* __restrict__ hc1,
                         const int* __restrict__ inv, const int* __restrict__ cl,
                         ushort* __restrict__ ycat){
  int i = blockIdx.x*256 + threadIdx.x;     // over NW*128 (16B each)
  if (i >= NW*128) return;
  int w = i >> 7, seg = i & 127;
  int iv = inv[w];
  ulonglong2 z; z.x = 0; z.y = 0;
  if (iv >= 0){
    const ushort* src = (((cl[w]-1)&1) ? hc0 : hc1) + (size_t)iv*CH + seg*8;
    z = *(const ulonglong2*)src;
  }
  *(ulonglong2*)(ycat + (size_t)w*CH + seg*8) = z;
}

// ---------- final linear ----------
__global__ __launch_bounds__(256) void k_final(
    const ushort* __restrict__ h1cat, const ushort* __restrict__ ycat,
    const float* __restrict__ lw, const float* __restrict__ lb,
    float* __restrict__ out)
{
  int i = blockIdx.x*256 + threadIdx.x;
  if (i >= NW*NCLS) return;
  int w = i / NCLS, o = i - w*NCLS;
  const ushort* hr = h1cat + (size_t)w*1024;
  const ushort* yr = ycat  + (size_t)w*1024;
  const float* wr = lw + (size_t)o*1024;
  float acc = lb[o];
  for (int k=0;k<1024;k+=4){
    float4 wv = *(const float4*)&wr[k];
    ushort4 a4 = *(const ushort4*)&hr[k];
    ushort4 b4 = *(const ushort4*)&yr[k];
    acc += (b2f(a4.x)+b2f(b4.x))*wv.x + (b2f(a4.y)+b2f(b4.y))*wv.y
         + (b2f(a4.z)+b2f(b4.z))*wv.z + (b2f(a4.w)+b2f(b4.w))*wv.w;
  }
  out[i] = acc;
}

extern "C" void kernel_launch(void* const* d_in, const int* in_sizes, int n_in,
                              void* d_out, int out_size, void* d_ws, size_t ws_size,
                              hipStream_t stream)
{
  const int*   words = (const int*)d_in[0];
  const int*   wnum  = (const int*)d_in[1];
  const int*   chars = (const int*)d_in[2];
  const int*   clens = (const int*)d_in[3];
  const float* wemb  = (const float*)d_in[4];
  const float* cemb  = (const float*)d_in[5];
  const float* l0Wih = (const float*)d_in[6];
  const float* l0Whh = (const float*)d_in[7];
  const float* l0b   = (const float*)d_in[8];
  const float* l1Wih = (const float*)d_in[9];
  const float* l1Whh = (const float*)d_in[10];
  const float* l1b   = (const float*)d_in[11];
  const float* cWih  = (const float*)d_in[12];
  const float* cWhh  = (const float*)d_in[13];
  const float* cb    = (const float*)d_in[14];
  const float* linW  = (const float*)d_in[15];
  const float* linb  = (const float*)d_in[16];
  float* out = (float*)d_out;

  // ---- static workspace layout (peak ~115 MB); char phase aliases word phase ----
  char* base = (char*)d_ws;
  const size_t MB = (size_t)1<<20;
  ushort* hc0    = (ushort*)(base);            // 16 MB (char)  | X region (word)
  ushort* hc1    = (ushort*)(base + 16*MB);    // 16 MB (char)  |
  float*  ccell  = (float*) (base + 32*MB);    // 32 MB (char)  |
  ushort* X      = (ushort*)(base);            // 64 MB (word)
  ushort* cwp    = (ushort*)(base + 64*MB);    //  8 MB (char)  | l1w 8MB (word)
  ushort* l1w    = (ushort*)(base + 64*MB);
  float*  cproj  = (float*) (base + 72*MB);    //  2 MB (char)  | embw 4MB | w1p 4MB (after X0)
  int*    chperm = (int*)   (base + 74*MB);    // 512 KB (char) |
  ushort* embw   = (ushort*)(base + 72*MB);
  ushort* w1p    = (ushort*)(base + 72*MB);
  ushort* ycat   = (ushort*)(base + 76*MB);    // 16 MB persistent
  ushort* h0cat  = (ushort*)(base + 92*MB);    // 16 MB (layer0 out) | h1cat after X1 GEMM
  ushort* h1cat  = (ushort*)(base + 92*MB);
  ushort* l0w    = (ushort*)(base + 108*MB);   //  2 MB
  ushort* w0p    = (ushort*)(base + 110*MB);   //  4 MB
  ushort* hbuf   = (ushort*)(base + 114*MB);                 // 256 KB [2][2][64][512] bf16
  int*    bar    = (int*)   (base + 114*MB + 256*1024);      // 8 B
  int*    inv    = (int*)   (base + 114*MB + 512*1024);      // 32 KB
  int*    cnt17  = (int*)   (base + 114*MB + 544*1024);      // 68 B
  int*    cntstep= (int*)   (base + 114*MB + 545*1024);      // 68 B
  int*    cur    = (int*)   (base + 114*MB + 546*1024);      // 68 B

  // ---- phase 0: char-path prep ----
  k_fill<<<1, 256, 0, stream>>>((uint32_t*)cnt17, 0u, 17);
  k_fill<<<(NW+255)/256, 256, 0, stream>>>((uint32_t*)inv, 0xFFFFFFFFu, NW);
  k_fill<<<(NW*CH/2+255)/256, 256, 0, stream>>>((uint32_t*)hc0, 0u, NW*CH/2);
  k_fill<<<(NW*CH+255)/256, 256, 0, stream>>>((uint32_t*)ccell, 0u, NW*CH);
  k_cwhhp<<<(CG*CH)/256, 256, 0, stream>>>(cWhh, cwp);
  k_cproj<<<(128*CG)/256, 256, 0, stream>>>(cemb, cWih, cb, cproj);
  k_hist<<<NW/256, 256, 0, stream>>>(wnum, clens, cnt17);
  k_scan<<<1, 1, 0, stream>>>(cnt17, cntstep, cur);
  k_scatter<<<NW/256, 256, 0, stream>>>(wnum, clens, chars, cur, inv, chperm);

  // ---- phase 1: char LSTM, 16 fused GEMM+gate steps over len-sorted valid words ----
  for (int t=0;t<WCH;t++){
    const ushort* hs = (t&1)? hc1 : hc0;
    ushort*       hd = (t&1)? hc0 : hc1;
    k_gemm<1><<<dim3(64,32,1), 256, 0, stream>>>(hs, CH, cwp, CH, 0,
        nullptr, nullptr, 0, 0, CH,
        cntstep, t, chperm, cproj, ccell, hd);
  }
  // ---- phase 2: gather final char h to word order; frees the 64MB char region ----
  k_gather<<<(NW*128+255)/256, 256, 0, stream>>>(hc0, hc1, inv, clens, ycat);

  // ---- phase 3: word path ----
  k_cvt<<<(2*G4*EDIM+255)/256, 256, 0, stream>>>(l0Wih, l0w, 2*G4*EDIM);
  k_cvt<<<(2*G4*1024+255)/256, 256, 0, stream>>>(l1Wih, l1w, 2*G4*1024);
  k_wwhhp<<<(2*G4*HDIM)/256, 256, 0, stream>>>(l0Whh, w0p);
  k_emb<<<(NW*EDIM)/256, 256, 0, stream>>>(words, wemb, embw);
  k_fill<<<(NW*512+255)/256, 256, 0, stream>>>((uint32_t*)h0cat, 0u, NW*512);
  k_fill<<<(32768+255)/256, 256, 0, stream>>>((uint32_t*)hbuf, 0u, 32768);   // slot 0
  k_fill<<<1, 256, 0, stream>>>((uint32_t*)bar, 0u, 2);

  // X0 = emb @ l0_Wih^T + b  (both dirs)
  k_gemm<0><<<dim3(64,16,2), 256, 0, stream>>>(embw, EDIM, l0w, EDIM, (size_t)G4*EDIM,
      X, l0b, (size_t)NW*G4, (size_t)G4, EDIM,
      nullptr, 0, nullptr, nullptr, nullptr, nullptr);

  // w1p overwrites embw region (embw fully consumed by X0 GEMM)
  k_wwhhp<<<(2*G4*HDIM)/256, 256, 0, stream>>>(l1Whh, w1p);

  // word layer 0 recurrence: ONE persistent launch (128 steps internally)
  k_wrec<<<32, 256, 0, stream>>>(hbuf, X, w0p, wnum, h0cat, bar);

  // X1 = h0cat @ l1_Wih^T + b   (fully consumes h0cat; h1cat aliases it afterwards)
  k_gemm<0><<<dim3(64,16,2), 256, 0, stream>>>(h0cat, 1024, l1w, 1024, (size_t)G4*1024,
      X, l1b, (size_t)NW*G4, (size_t)G4, 1024,
      nullptr, 0, nullptr, nullptr, nullptr, nullptr);

  k_fill<<<(NW*512+255)/256, 256, 0, stream>>>((uint32_t*)h1cat, 0u, NW*512);
  k_fill<<<(32768+255)/256, 256, 0, stream>>>((uint32_t*)hbuf, 0u, 32768);   // reset slot 0
  k_fill<<<1, 256, 0, stream>>>((uint32_t*)bar, 0u, 2);

  // word layer 1 recurrence
  k_wrec<<<32, 256, 0, stream>>>(hbuf, X, w1p, wnum, h1cat, bar);

  k_final<<<(NW*NCLS+255)/256, 256, 0, stream>>>(h1cat, ycat, linW, linb, out);
}

// Round 8
// 4303.957 us; speedup vs baseline: 4.6579x; 1.0298x over previous
//
#include <hip/hip_runtime.h>
#include <stdint.h>

#define SLEN 128
#define NW 8192          // B*S words
#define WCH 16           // chars per word
#define EDIM 256
#define HDIM 512
#define G4 2048          // 4*H word-gate width
#define CH 1024          // char hidden (2H)
#define CG 4096          // 4*CH char-gate width
#define NCLS 20

typedef __attribute__((ext_vector_type(4))) float f32x4;
typedef __attribute__((ext_vector_type(8))) short s16x8;

__device__ __forceinline__ ushort f2b(float f){
  uint32_t u = __float_as_uint(f);
  return (ushort)((u + 0x7FFFu + ((u>>16)&1u)) >> 16);
}
__device__ __forceinline__ float b2f(ushort s){ return __uint_as_float(((uint32_t)s)<<16); }
__device__ __forceinline__ float sigf(float x){ return 1.f/(1.f+__expf(-x)); }
__device__ __forceinline__ float tanhf_(float x){
  float t = fminf(fmaxf(2.f*x,-30.f),30.f);
  float e = __expf(t);
  return (e-1.f)/(e+1.f);
}

__device__ __forceinline__ void gl16(const ushort* g, ushort* l){
  __builtin_amdgcn_global_load_lds((const __attribute__((address_space(1))) uint32_t*)g,
                                   (__attribute__((address_space(3))) uint32_t*)l, 16, 0, 0);
}

// ---------- utility ----------
__global__ void k_fill(uint32_t* __restrict__ p, uint32_t v, int n){
  int i = blockIdx.x*256 + threadIdx.x;
  if (i < n) p[i] = v;
}

__global__ void k_cvt(const float* __restrict__ s, ushort* __restrict__ d, int n){
  int i = blockIdx.x*256 + threadIdx.x;
  if (i < n) d[i] = f2b(s[i]);
}

// permute c_Whh rows: dst row dr = nb*128 + g*32 + wn*16 + hl  <-  src row g*1024 + (nb*32+wn*16+hl)
__global__ void k_cwhhp(const float* __restrict__ s, ushort* __restrict__ d){
  int i = blockIdx.x*256 + threadIdx.x;           // over 4096*1024
  int dr = i >> 10, k = i & 1023;
  int nb = dr >> 7, w7 = dr & 127;
  int g = w7 >> 5, wn = (w7>>4)&1, hl = w7&15;
  int h = nb*32 + wn*16 + hl;
  d[i] = f2b(s[(size_t)(g*1024 + h)*1024 + k]);
}

// permute word Whh rows (per layer): [2 dirs][2048][512] fp32 -> bf16 permuted
// dst row dr = y*128 + g*32 + wn*16 + hl  <-  src row g*512 + (y*32+wn*16+hl)
__global__ void k_wwhhp(const float* __restrict__ s, ushort* __restrict__ d){
  int i = blockIdx.x*256 + threadIdx.x;           // over 2*2048*512
  int dr = i >> 9, k = i & 511;
  int dir = dr >> 11; int r = dr & 2047;
  int y = r >> 7, w7 = r & 127;
  int g = w7 >> 5, wn = (w7>>4)&1, hl = w7&15;
  int h = y*32 + wn*16 + hl;
  d[i] = f2b(s[((size_t)dir*2048 + g*512 + h)*512 + k]);
}

__global__ void k_emb(const int* __restrict__ words, const float* __restrict__ we,
                      ushort* __restrict__ d){
  int i = blockIdx.x*256 + threadIdx.x;           // NW*EDIM
  int w = i >> 8, e = i & 255;
  d[i] = f2b(we[(size_t)words[w]*EDIM + e]);
}

// char_proj[c][perm_col] = c_b[j] + char_emb[c] . c_Wih[j]   (perm layout as k_cwhhp)
__global__ void k_cproj(const float* __restrict__ cemb, const float* __restrict__ cwih,
                        const float* __restrict__ cb, float* __restrict__ out){
  int i = blockIdx.x*256 + threadIdx.x;           // 128*4096
  int c = i >> 12, p = i & 4095;
  int nb = p >> 7, w7 = p & 127;
  int g = w7>>5, wn = (w7>>4)&1, hl = w7&15;
  int j = g*1024 + nb*32 + wn*16 + hl;
  const float* a = cemb + (size_t)c*EDIM;
  const float* b = cwih + (size_t)j*EDIM;
  float acc = cb[j];
  for (int k=0;k<EDIM;k+=4){
    float4 av = *(const float4*)&a[k]; float4 bv = *(const float4*)&b[k];
    acc += av.x*bv.x + av.y*bv.y + av.z*bv.z + av.w*bv.w;
  }
  out[i] = acc;
}

__global__ void k_hist(const int* __restrict__ wn, const int* __restrict__ cl,
                       int* __restrict__ cnt17){
  int w = blockIdx.x*256 + threadIdx.x; if (w >= NW) return;
  int b = w >> 7, s = w & 127;
  if (s < wn[b]) atomicAdd(&cnt17[cl[w]], 1);   // cl in [1,16]
}

__global__ void k_scan(const int* __restrict__ cnt17, int* __restrict__ cnt_step,
                       int* __restrict__ cur){
  if (threadIdx.x==0 && blockIdx.x==0){
    cnt_step[16] = 0;
    for (int t=15;t>=0;t--) cnt_step[t] = cnt_step[t+1] + cnt17[t+1];
    for (int l=1;l<=16;l++) cur[l] = cnt_step[l];   // bucket cursors (len descending order)
  }
}

__global__ void k_scatter(const int* __restrict__ wn, const int* __restrict__ cl,
                          const int* __restrict__ chars, int* __restrict__ cur,
                          int* __restrict__ inv, int* __restrict__ chperm){
  int w = blockIdx.x*256 + threadIdx.x; if (w >= NW) return;
  int b = w >> 7, s = w & 127;
  if (s < wn[b]){
    int len = cl[w];
    int pos = atomicAdd(&cur[len], 1);
    inv[w] = pos;
    for (int j=0;j<WCH;j++) chperm[pos*WCH + j] = chars[w*WCH + j];
  }
}

// ---------- MFMA GEMM: C = A[M,K] @ B[N,K]^T, bf16 in, fp32 acc ----------
// EPI=0: X projection (out bf16 = acc + bias[col]), grid (M/128, N/128, ndir)
// EPI=1: char-LSTM step epilogue (gate fusion), grid (64, 32, 1)
template<int EPI>
__global__ __launch_bounds__(256) void k_gemm(
    const ushort* __restrict__ A, int ldA,
    const ushort* __restrict__ Bm, int ldB, size_t bStrideZ,
    ushort* __restrict__ outX, const float* __restrict__ bias,
    size_t oStrideZ, size_t biasStrideZ, int K,
    const int* __restrict__ cnt_step, int tstep,
    const int* __restrict__ chperm, const float* __restrict__ cproj,
    float* __restrict__ ccell, ushort* __restrict__ hcdst)
{
  int cntv = 0;
  if (EPI==1){ cntv = cnt_step[tstep]; if ((int)(blockIdx.x*128) >= cntv) return; }
  __shared__ __align__(16) ushort As[128*64];
  __shared__ __align__(16) ushort Bs[128*64];
  int tid = threadIdx.x, wid = tid>>6, lane = tid&63;
  int wm = wid>>1, wn = wid&1;
  int l15 = lane&15, l4 = lane>>4;
  const ushort* Ab = A + (size_t)blockIdx.x*128*ldA;
  const ushort* Bb = Bm + (size_t)blockIdx.z*bStrideZ + (size_t)blockIdx.y*128*ldB;
  f32x4 acc[4][4];
  #pragma unroll
  for (int i=0;i<4;i++)
    #pragma unroll
    for (int j=0;j<4;j++) acc[i][j] = f32x4{0.f,0.f,0.f,0.f};

  for (int k0=0; k0<K; k0+=64){
    // stage A and B tiles; LDS dest linear per-wave, global source pre-swizzled:
    // LDS 16B-slot cp of row holds global chunk c = cp ^ (row&7)
    #pragma unroll
    for (int i=0;i<4;i++){
      int fcb = (i*4 + wid)*64;
      int fc = fcb + lane;
      int row = fc>>3, cp = fc&7, c = cp ^ (row&7);
      gl16(Ab + (size_t)row*ldA + k0 + c*8, As + fcb*8);
    }
    #pragma unroll
    for (int i=0;i<4;i++){
      int fcb = (i*4 + wid)*64;
      int fc = fcb + lane;
      int row = fc>>3, cp = fc&7, c = cp ^ (row&7);
      gl16(Bb + (size_t)row*ldB + k0 + c*8, Bs + fcb*8);
    }
    __syncthreads();
    #pragma unroll
    for (int kw=0; kw<2; kw++){
      s16x8 af[4], bfr[4];
      #pragma unroll
      for (int mf=0; mf<4; mf++){
        int r = wm*64 + mf*16 + l15;
        int slot = (kw*4 + l4) ^ (r&7);
        af[mf] = *(const s16x8*)&As[r*64 + slot*8];
      }
      #pragma unroll
      for (int nf=0; nf<4; nf++){
        int r = (EPI==1) ? (nf*32 + wn*16 + l15) : (wn*64 + nf*16 + l15);
        int slot = (kw*4 + l4) ^ (r&7);
        bfr[nf] = *(const s16x8*)&Bs[r*64 + slot*8];
      }
      #pragma unroll
      for (int mf=0; mf<4; mf++)
        #pragma unroll
        for (int nf=0; nf<4; nf++)
          acc[mf][nf] = __builtin_amdgcn_mfma_f32_16x16x32_bf16(af[mf], bfr[nf], acc[mf][nf], 0,0,0);
    }
    __syncthreads();
  }

  if (EPI==0){
    ushort* op = outX + blockIdx.z*oStrideZ;
    const float* bp = bias + blockIdx.z*biasStrideZ;
    #pragma unroll
    for (int mf=0; mf<4; mf++){
      #pragma unroll
      for (int r=0;r<4;r++){
        int row = blockIdx.x*128 + wm*64 + mf*16 + l4*4 + r;
        #pragma unroll
        for (int nf=0;nf<4;nf++){
          int col = blockIdx.y*128 + wn*64 + nf*16 + l15;
          op[(size_t)row*G4 + col] = f2b(acc[mf][nf][r] + bp[col]);
        }
      }
    }
  } else {
    int hb = blockIdx.y*32 + wn*16 + l15;     // h index in [0,1024)
    #pragma unroll
    for (int mf=0; mf<4; mf++){
      #pragma unroll
      for (int r=0;r<4;r++){
        int row = blockIdx.x*128 + wm*64 + mf*16 + l4*4 + r;
        if (row < cntv){
          int cid = chperm[row*WCH + tstep];
          const float* cp = cproj + (size_t)cid*CG + blockIdx.y*128 + wn*16 + l15;
          float zi = acc[mf][0][r] + cp[0];
          float zf = acc[mf][1][r] + cp[32];
          float zg = acc[mf][2][r] + cp[64];
          float zo = acc[mf][3][r] + cp[96];
          size_t ix = (size_t)row*CH + hb;
          float c = ccell[ix];
          float cn = sigf(zf)*c + sigf(zi)*tanhf_(zg);
          ccell[ix] = cn;
          hcdst[ix] = f2b(sigf(zo)*tanhf_(cn));
        }
      }
    }
  }
}

// ---------- persistent word-path LSTM recurrence (one launch per layer) ----------
// grid 32: bid = dir*16 + y. Block owns perm-cols [y*128, y*128+128) of its dir.
// W slice LDS-resident (128KB). h double-buffered in global hbuf[2][2][64][512] bf16.
// c-state + frozen-h in registers. Per-dir 16-block device-scope barrier per step.
// A-tile staging is double-buffered with counted vmcnt (T4): tile kt+1 in flight
// while tile kt is consumed -> one exposed latency per step instead of eight.
__global__ __launch_bounds__(256) void k_wrec(
    ushort* __restrict__ hbuf,          // [2 slots][2 dirs][64][512]
    const ushort* __restrict__ X,       // [2][NW][G4] bf16 (x@Wih^T + b)
    const ushort* __restrict__ Wp,      // [2][2048][512] permuted bf16
    const int* __restrict__ lens,
    ushort* __restrict__ outcat,        // [NW][1024] bf16
    int* __restrict__ bar)              // [2] per-dir counters, zeroed before launch
{
  __shared__ __align__(16) ushort Ws[8*128*64];   // 128 KB
  __shared__ __align__(16) ushort As[2*64*64];    //  16 KB (double-buffered)
  int tid = threadIdx.x, wid = tid>>6, lane = tid&63;
  int l15 = lane&15, l4 = lane>>4;
  int y = blockIdx.x & 15, dir = blockIdx.x >> 4;
  const ushort* Wb = Wp + ((size_t)dir*2048 + (size_t)y*128)*512;

  // ---- prologue: stage W slice into LDS (8 K-tiles of [128][64], swizzled like Bs) ----
  #pragma unroll
  for (int kt=0; kt<8; ++kt)
    #pragma unroll
    for (int i=0;i<4;i++){
      int fcb = (i*4 + wid)*64;
      int fc = fcb + lane;
      int row = fc>>3, cp = fc&7, c = cp ^ (row&7);
      gl16(Wb + (size_t)row*512 + kt*64 + c*8, Ws + kt*8192 + fcb*8);
    }
  asm volatile("s_waitcnt vmcnt(0)" ::: "memory");
  __builtin_amdgcn_sched_barrier(0);
  __builtin_amdgcn_s_barrier();

  int b0 = wid*16 + l4*4;
  int lenv[4];
  #pragma unroll
  for (int r=0;r<4;r++) lenv[r] = lens[b0+r];
  float  cacc[2][4];
  ushort hprev[2][4];
  #pragma unroll
  for (int wn=0;wn<2;wn++)
    #pragma unroll
    for (int r=0;r<4;r++){ cacc[wn][r]=0.f; hprev[wn][r]=0; }

  int* mybar = bar + dir;

  for (int t=0;t<SLEN;t++){
    const ushort* hsrc = hbuf + ((size_t)((t&1)*2 + dir))*32768;
    ushort*       hdst = hbuf + ((size_t)((((t&1)^1))*2 + dir))*32768;
    f32x4 acc[8];
    #pragma unroll
    for (int n=0;n<8;n++) acc[n] = f32x4{0.f,0.f,0.f,0.f};

    // stage tile 0 into buffer half 0
    #pragma unroll
    for (int i=0;i<2;i++){
      int fcb = (i*4 + wid)*64;
      int fc = fcb + lane;
      int row = fc>>3, cp = fc&7, c = cp ^ (row&7);
      gl16(hsrc + (size_t)row*512 + c*8, As + fcb*8);
    }
    for (int kt=0; kt<8; ++kt){
      const ushort* curb = As + (kt&1)*4096;
      if (kt<7){
        ushort* nxb = As + ((kt+1)&1)*4096;
        #pragma unroll
        for (int i=0;i<2;i++){
          int fcb = (i*4 + wid)*64;
          int fc = fcb + lane;
          int row = fc>>3, cp = fc&7, c = cp ^ (row&7);
          gl16(hsrc + (size_t)row*512 + (kt+1)*64 + c*8, nxb + fcb*8);
        }
        asm volatile("s_waitcnt vmcnt(2)" ::: "memory");   // tile kt done; kt+1 in flight
      } else {
        asm volatile("s_waitcnt vmcnt(0)" ::: "memory");
      }
      __builtin_amdgcn_sched_barrier(0);
      __builtin_amdgcn_s_barrier();
      #pragma unroll
      for (int kw=0; kw<2; kw++){
        s16x8 af;
        { int r = wid*16 + l15; int slot = (kw*4 + l4) ^ (r&7);
          af = *(const s16x8*)&curb[r*64 + slot*8]; }
        #pragma unroll
        for (int nf=0; nf<8; nf++){
          int rr = nf*16 + l15; int slot = (kw*4 + l4) ^ (rr&7);
          s16x8 bfr = *(const s16x8*)&Ws[kt*8192 + rr*64 + slot*8];
          acc[nf] = __builtin_amdgcn_mfma_f32_16x16x32_bf16(af, bfr, acc[nf], 0,0,0);
        }
      }
      __builtin_amdgcn_s_barrier();   // all waves done with curb before it is re-staged
    }

    // ---- gate-fused epilogue (identical math to k_wstep) ----
    #pragma unroll
    for (int wn=0;wn<2;wn++){
      int h = y*32 + wn*16 + l15;
      #pragma unroll
      for (int r=0;r<4;r++){
        int b = b0 + r;
        ushort hnew;
        if (t < lenv[r]){
          int pos = dir ? (lenv[r]-1-t) : t;
          size_t xbase = ((size_t)dir*NW + (size_t)b*SLEN + pos)*G4 + h;
          float zi = acc[0+wn][r] + b2f(X[xbase]);
          float zf = acc[2+wn][r] + b2f(X[xbase + 512]);
          float zg = acc[4+wn][r] + b2f(X[xbase + 1024]);
          float zo = acc[6+wn][r] + b2f(X[xbase + 1536]);
          float cn = sigf(zf)*cacc[wn][r] + sigf(zi)*tanhf_(zg);
          cacc[wn][r] = cn;
          float hv = sigf(zo)*tanhf_(cn);
          hnew = f2b(hv);
          outcat[((size_t)b*SLEN + pos)*1024 + dir*HDIM + h] = hnew;
        } else {
          hnew = hprev[wn][r];
        }
        hprev[wn][r] = hnew;
        hdst[(size_t)b*512 + h] = hnew;
      }
    }

    // ---- per-dir grid barrier: release stores -> count -> acquire ----
    __syncthreads();                       // drains vmcnt: block's stores in L2
    if (tid==0){
      __threadfence();                     // agent release: L2 writeback to coherent point
      __hip_atomic_fetch_add(mybar, 1, __ATOMIC_RELEASE, __HIP_MEMORY_SCOPE_AGENT);
      int tgt = 16*(t+1);
      while (__hip_atomic_load(mybar, __ATOMIC_ACQUIRE, __HIP_MEMORY_SCOPE_AGENT) < tgt)
        __builtin_amdgcn_s_sleep(8);
      __threadfence();                     // agent acquire: invalidate L1/L2
    }
    __syncthreads();
  }
}

// ---------- gather final char h into word order (zeros for invalid words) ----------
__global__ void k_gather(const ushort* __restrict__ hc0, const ushort* __restrict__ hc1,
                         const int* __restrict__ inv, const int* __restrict__ cl,
                         ushort* __restrict__ ycat){
  int i = blockIdx.x*256 + threadIdx.x;     // over NW*128 (16B each)
  if (i >= NW*128) return;
  int w = i >> 7, seg = i & 127;
  int iv = inv[w];
  ulonglong2 z; z.x = 0; z.y = 0;
  if (iv >= 0){
    const ushort* src = (((cl[w]-1)&1) ? hc0 : hc1) + (size_t)iv*CH + seg*8;
    z = *(const ulonglong2*)src;
  }
  *(ulonglong2*)(ycat + (size_t)w*CH + seg*8) = z;
}

// ---------- final linear ----------
__global__ __launch_bounds__(256) void k_final(
    const ushort* __restrict__ h1cat, const ushort* __restrict__ ycat,
    const float* __restrict__ lw, const float* __restrict__ lb,
    float* __restrict__ out)
{
  int i = blockIdx.x*256 + threadIdx.x;
  if (i >= NW*NCLS) return;
  int w = i / NCLS, o = i - w*NCLS;
  const ushort* hr = h1cat + (size_t)w*1024;
  const ushort* yr = ycat  + (size_t)w*1024;
  const float* wr = lw + (size_t)o*1024;
  float acc = lb[o];
  for (int k=0;k<1024;k+=4){
    float4 wv = *(const float4*)&wr[k];
    ushort4 a4 = *(const ushort4*)&hr[k];
    ushort4 b4 = *(const ushort4*)&yr[k];
    acc += (b2f(a4.x)+b2f(b4.x))*wv.x + (b2f(a4.y)+b2f(b4.y))*wv.y
         + (b2f(a4.z)+b2f(b4.z))*wv.z + (b2f(a4.w)+b2f(b4.w))*wv.w;
  }
  out[i] = acc;
}

extern "C" void kernel_launch(void* const* d_in, const int* in_sizes, int n_in,
                              void* d_out, int out_size, void* d_ws, size_t ws_size,
                              hipStream_t stream)
{
  const int*   words = (const int*)d_in[0];
  const int*   wnum  = (const int*)d_in[1];
  const int*   chars = (const int*)d_in[2];
  const int*   clens = (const int*)d_in[3];
  const float* wemb  = (const float*)d_in[4];
  const float* cemb  = (const float*)d_in[5];
  const float* l0Wih = (const float*)d_in[6];
  const float* l0Whh = (const float*)d_in[7];
  const float* l0b   = (const float*)d_in[8];
  const float* l1Wih = (const float*)d_in[9];
  const float* l1Whh = (const float*)d_in[10];
  const float* l1b   = (const float*)d_in[11];
  const float* cWih  = (const float*)d_in[12];
  const float* cWhh  = (const float*)d_in[13];
  const float* cb    = (const float*)d_in[14];
  const float* linW  = (const float*)d_in[15];
  const float* linb  = (const float*)d_in[16];
  float* out = (float*)d_out;

  // ---- static workspace layout (peak ~115 MB); char phase aliases word phase ----
  char* base = (char*)d_ws;
  const size_t MB = (size_t)1<<20;
  ushort* hc0    = (ushort*)(base);            // 16 MB (char)  | X region (word)
  ushort* hc1    = (ushort*)(base + 16*MB);    // 16 MB (char)  |
  float*  ccell  = (float*) (base + 32*MB);    // 32 MB (char)  |
  ushort* X      = (ushort*)(base);            // 64 MB (word)
  ushort* cwp    = (ushort*)(base + 64*MB);    //  8 MB (char)  | l1w 8MB (word)
  ushort* l1w    = (ushort*)(base + 64*MB);
  float*  cproj  = (float*) (base + 72*MB);    //  2 MB (char)  | embw 4MB | w1p 4MB (after X0)
  int*    chperm = (int*)   (base + 74*MB);    // 512 KB (char) |
  ushort* embw   = (ushort*)(base + 72*MB);
  ushort* w1p    = (ushort*)(base + 72*MB);
  ushort* ycat   = (ushort*)(base + 76*MB);    // 16 MB persistent
  ushort* h0cat  = (ushort*)(base + 92*MB);    // 16 MB (layer0 out) | h1cat after X1 GEMM
  ushort* h1cat  = (ushort*)(base + 92*MB);
  ushort* l0w    = (ushort*)(base + 108*MB);   //  2 MB
  ushort* w0p    = (ushort*)(base + 110*MB);   //  4 MB
  ushort* hbuf   = (ushort*)(base + 114*MB);                 // 256 KB [2][2][64][512] bf16
  int*    bar    = (int*)   (base + 114*MB + 256*1024);      // 8 B
  int*    inv    = (int*)   (base + 114*MB + 512*1024);      // 32 KB
  int*    cnt17  = (int*)   (base + 114*MB + 544*1024);      // 68 B
  int*    cntstep= (int*)   (base + 114*MB + 545*1024);      // 68 B
  int*    cur    = (int*)   (base + 114*MB + 546*1024);      // 68 B

  // ---- phase 0: char-path prep ----
  k_fill<<<1, 256, 0, stream>>>((uint32_t*)cnt17, 0u, 17);
  k_fill<<<(NW+255)/256, 256, 0, stream>>>((uint32_t*)inv, 0xFFFFFFFFu, NW);
  k_fill<<<(NW*CH/2+255)/256, 256, 0, stream>>>((uint32_t*)hc0, 0u, NW*CH/2);
  k_fill<<<(NW*CH+255)/256, 256, 0, stream>>>((uint32_t*)ccell, 0u, NW*CH);
  k_cwhhp<<<(CG*CH)/256, 256, 0, stream>>>(cWhh, cwp);
  k_cproj<<<(128*CG)/256, 256, 0, stream>>>(cemb, cWih, cb, cproj);
  k_hist<<<NW/256, 256, 0, stream>>>(wnum, clens, cnt17);
  k_scan<<<1, 1, 0, stream>>>(cnt17, cntstep, cur);
  k_scatter<<<NW/256, 256, 0, stream>>>(wnum, clens, chars, cur, inv, chperm);

  // ---- phase 1: char LSTM, 16 fused GEMM+gate steps over len-sorted valid words ----
  for (int t=0;t<WCH;t++){
    const ushort* hs = (t&1)? hc1 : hc0;
    ushort*       hd = (t&1)? hc0 : hc1;
    k_gemm<1><<<dim3(64,32,1), 256, 0, stream>>>(hs, CH, cwp, CH, 0,
        nullptr, nullptr, 0, 0, CH,
        cntstep, t, chperm, cproj, ccell, hd);
  }
  // ---- phase 2: gather final char h to word order; frees the 64MB char region ----
  k_gather<<<(NW*128+255)/256, 256, 0, stream>>>(hc0, hc1, inv, clens, ycat);

  // ---- phase 3: word path ----
  k_cvt<<<(2*G4*EDIM+255)/256, 256, 0, stream>>>(l0Wih, l0w, 2*G4*EDIM);
  k_cvt<<<(2*G4*1024+255)/256, 256, 0, stream>>>(l1Wih, l1w, 2*G4*1024);
  k_wwhhp<<<(2*G4*HDIM)/256, 256, 0, stream>>>(l0Whh, w0p);
  k_emb<<<(NW*EDIM)/256, 256, 0, stream>>>(words, wemb, embw);
  k_fill<<<(NW*512+255)/256, 256, 0, stream>>>((uint32_t*)h0cat, 0u, NW*512);
  k_fill<<<(32768+255)/256, 256, 0, stream>>>((uint32_t*)hbuf, 0u, 32768);   // slot 0
  k_fill<<<1, 256, 0, stream>>>((uint32_t*)bar, 0u, 2);

  // X0 = emb @ l0_Wih^T + b  (both dirs)
  k_gemm<0><<<dim3(64,16,2), 256, 0, stream>>>(embw, EDIM, l0w, EDIM, (size_t)G4*EDIM,
      X, l0b, (size_t)NW*G4, (size_t)G4, EDIM,
      nullptr, 0, nullptr, nullptr, nullptr, nullptr);

  // w1p overwrites embw region (embw fully consumed by X0 GEMM)
  k_wwhhp<<<(2*G4*HDIM)/256, 256, 0, stream>>>(l1Whh, w1p);

  // word layer 0 recurrence: ONE persistent launch (128 steps internally)
  k_wrec<<<32, 256, 0, stream>>>(hbuf, X, w0p, wnum, h0cat, bar);

  // X1 = h0cat @ l1_Wih^T + b   (fully consumes h0cat; h1cat aliases it afterwards)
  k_gemm<0><<<dim3(64,16,2), 256, 0, stream>>>(h0cat, 1024, l1w, 1024, (size_t)G4*1024,
      X, l1b, (size_t)NW*G4, (size_t)G4, 1024,
      nullptr, 0, nullptr, nullptr, nullptr, nullptr);

  k_fill<<<(NW*512+255)/256, 256, 0, stream>>>((uint32_t*)h1cat, 0u, NW*512);
  k_fill<<<(32768+255)/256, 256, 0, stream>>>((uint32_t*)hbuf, 0u, 32768);   // reset slot 0
  k_fill<<<1, 256, 0, stream>>>((uint32_t*)bar, 0u, 2);

  // word layer 1 recurrence
  k_wrec<<<32, 256, 0, stream>>>(hbuf, X, w1p, wnum, h1cat, bar);

  k_final<<<(NW*NCLS+255)/256, 256, 0, stream>>>(h1cat, ycat, linW, linb, out);
}